// Round 12
// baseline (1353.041 us; speedup 1.0000x reference)
//
#include <hip/hip_runtime.h>
#include <math.h>

// ---------------- problem constants ----------------
#define N_NODES 50000
#define N_EDGES 800000
#define NF 92           // node features
#define EF 41           // edge features
#define GF 180          // global attr
#define NEP 48          // padded f16 edge_attr row (dst-sorted)

#define WCN_ELEMS (3 * 24 * 64 * 8)   // node-GEMM weights per layer (bf16 hi/lo)
#define WCE_ELEMS (2 * 12 * 64 * 8)   // edge-GEMM weights per layer (f16 hi/lo)
#define WCF_ELEMS (3 * 6 * 64 * 8)    // fc1 weights (bf16 hi/lo)

typedef __attribute__((ext_vector_type(8))) short bf16x8;
typedef __attribute__((ext_vector_type(8))) _Float16 f16x8;
typedef __attribute__((ext_vector_type(2))) _Float16 f16x2;
typedef __attribute__((ext_vector_type(4))) float f32x4;

#define L2E 1.44269504f
#define LN2 0.69314718f

__device__ __forceinline__ float fast_sigmoid(float x) {
    return __builtin_amdgcn_rcpf(1.0f + __builtin_amdgcn_exp2f(-x * L2E));
}
__device__ __forceinline__ float fast_softplus(float x) {
    float t = __builtin_amdgcn_exp2f(-fabsf(x) * L2E);
    return fmaxf(x, 0.0f) + __builtin_amdgcn_logf(1.0f + t) * LN2;
}
__device__ __forceinline__ float fast_silu(float x) { return x * fast_sigmoid(x); }

__device__ __forceinline__ unsigned short f2bf(float x) {
    union { float f; unsigned u; } v; v.f = x;
    unsigned r = v.u + 0x7FFF + ((v.u >> 16) & 1);   // RNE
    return (unsigned short)(r >> 16);
}
__device__ __forceinline__ float bf2f(unsigned short h) {
    union { unsigned u; float f; } v; v.u = ((unsigned)h) << 16; return v.f;
}

// bijective XCD-aware block swizzle (m204 variant)
__device__ __forceinline__ int xcd_swz(int bid, int nwg) {
    int q = nwg >> 3, r = nwg & 7;
    int xcd = bid & 7, idx = bid >> 3;
    return (xcd < r ? xcd * (q + 1) : r * (q + 1) + (xcd - r) * q) + idx;
}

// load 8 fp32 from a 92-float row at cols [c16*8, c16*8+8), zero-padded past 91
__device__ __forceinline__ void load8f(const float* __restrict__ rowp, int c16, float v[8]) {
    if (c16 < 11) {
        float4 a = *(const float4*)(rowp + c16 * 8);
        float4 b = *(const float4*)(rowp + c16 * 8 + 4);
        v[0]=a.x; v[1]=a.y; v[2]=a.z; v[3]=a.w; v[4]=b.x; v[5]=b.y; v[6]=b.z; v[7]=b.w;
    } else {
        float4 a = *(const float4*)(rowp + 88);
        v[0]=a.x; v[1]=a.y; v[2]=a.z; v[3]=a.w; v[4]=0.f; v[5]=0.f; v[6]=0.f; v[7]=0.f;
    }
}

// ---------------- sort infra: counting sort of edges by dst ----------------
__global__ __launch_bounds__(256) void hist_kernel(const int* __restrict__ ei,
                                                   int* __restrict__ bins)
{
    int e = blockIdx.x * 256 + threadIdx.x;
    if (e < N_EDGES) atomicAdd(&bins[ei[N_EDGES + e]], 1);
}

__global__ __launch_bounds__(1024) void scan_kernel(const int* __restrict__ bins,
                                                    int* __restrict__ cursor)
{
    __shared__ int tot[1024];
    const int t = threadIdx.x;
    const int C = (N_NODES + 1023) / 1024;
    const int i0 = t * C, i1 = min(i0 + C, N_NODES);
    int s = 0;
    for (int i = i0; i < i1; ++i) s += bins[i];
    tot[t] = s;
    __syncthreads();
    for (int off = 1; off < 1024; off <<= 1) {
        int v = (t >= off) ? tot[t - off] : 0;
        __syncthreads();
        tot[t] += v;
        __syncthreads();
    }
    int run = tot[t] - s;   // exclusive base
    for (int i = i0; i < i1; ++i) { cursor[i] = run; run += bins[i]; }
}

__global__ __launch_bounds__(256) void place_kernel(const int* __restrict__ ei,
                                                    int* __restrict__ cursor,
                                                    int* __restrict__ perm,
                                                    int* __restrict__ invp,
                                                    int* __restrict__ s_src,
                                                    int* __restrict__ s_dst)
{
    int e = blockIdx.x * 256 + threadIdx.x;
    if (e < N_EDGES) {
        int d = ei[N_EDGES + e];
        int pos = atomicAdd(&cursor[d], 1);
        perm[pos] = e;
        invp[e] = pos;
        s_dst[pos] = d;
        s_src[pos] = ei[e];
    }
}

// ---------------- one-time: scatter ea into dst-sorted f16 rows (coalesced read) ----------------
__global__ __launch_bounds__(256) void permute_ea16s(const float* __restrict__ ea,
                                                     const int* __restrict__ invp,
                                                     _Float16* __restrict__ ebf)
{
    long i = (long)blockIdx.x * 256 + threadIdx.x;
    if (i >= (long)N_EDGES * NEP) return;
    long e = i / NEP; int c = (int)(i - e * NEP);
    float v = (c < EF) ? ea[e * EF + c] : 0.0f;
    ebf[(size_t)invp[e] * NEP + c] = (_Float16)v;
}

// ---------------- merged weight conversion (all layers, node+edge+fc) ----------------
__global__ __launch_bounds__(256) void convert_all(
    const float* __restrict__ Wf0, const float* __restrict__ Ws0,
    const float* __restrict__ Wf1, const float* __restrict__ Ws1,
    const float* __restrict__ Wf2, const float* __restrict__ Ws2,
    const float* __restrict__ fc1W,
    unsigned short* __restrict__ WcNh, unsigned short* __restrict__ WcNl,
    _Float16* __restrict__ WcEh, _Float16* __restrict__ WcEl,
    unsigned short* __restrict__ WcFh, unsigned short* __restrict__ WcFl)
{
    const int bid = blockIdx.x;
    if (bid < 432) {
        int l = bid / 144;
        int idx = (bid - l * 144) * 256 + threadIdx.x;
        if (idx >= 36864) return;
        const float* Wf = (l == 0) ? Wf0 : (l == 1) ? Wf1 : Wf2;
        const float* Ws = (l == 0) ? Ws0 : (l == 1) ? Ws1 : Ws2;
        int j    = idx & 7;
        int lane = (idx >> 3) & 63;
        int nt   = (idx >> 9) % 24;
        int ks   = idx / (24 * 512);
        int k = ks * 32 + ((lane >> 4) * 8) + j;
        int n = nt * 16 + (lane & 15);
        int t = n / 96, col = n % 96;
        float val = 0.f;
        if (k < 92 && col < 92) {
            const float* W = (t < 2) ? Wf : Ws;
            int rowoff = (t & 1) ? 92 : 0;
            val = W[(rowoff + k) * NF + col];
        }
        unsigned short hi = f2bf(val);
        size_t o = (size_t)l * 36864 + idx;
        WcNh[o] = hi;
        WcNl[o] = f2bf(val - bf2f(hi));
    } else if (bid < 576) {
        int b2 = bid - 432;
        int l = b2 / 48;
        int idx = (b2 - l * 48) * 256 + threadIdx.x;
        if (idx >= 12288) return;
        const float* Wf = (l == 0) ? Wf0 : (l == 1) ? Wf1 : Wf2;
        const float* Ws = (l == 0) ? Ws0 : (l == 1) ? Ws1 : Ws2;
        int j    = idx & 7;
        int lane = (idx >> 3) & 63;
        int nt   = (idx >> 9) % 12;
        int ks   = idx / (12 * 512);
        int k = ks * 32 + ((lane >> 4) * 8) + j;
        int n = nt * 16 + (lane & 15);
        float val = 0.f;
        if (k < EF) {
            if (n < 92)                  val = Wf[(184 + k) * NF + n];
            else if (n >= 96 && n < 188) val = Ws[(184 + k) * NF + (n - 96)];
        }
        _Float16 hi = (_Float16)val;
        size_t o = (size_t)l * 12288 + idx;
        WcEh[o] = hi;
        WcEl[o] = (_Float16)(val - (float)hi);
    } else {
        int idx = (bid - 576) * 256 + threadIdx.x;
        if (idx >= WCF_ELEMS) return;
        int j    = idx & 7;
        int lane = (idx >> 3) & 63;
        int nt   = (idx >> 9) % 6;
        int ks   = idx / (6 * 512);
        int k = ks * 32 + ((lane >> 4) * 8) + j;
        int n = nt * 16 + (lane & 15);
        float val = (k < 92 && n < 92) ? fc1W[k * NF + n] : 0.f;
        unsigned short hi = f2bf(val);
        WcFh[idx] = hi;
        WcFl[idx] = f2bf(val - bf2f(hi));
    }
}

// ---------------- fused node GEMM ----------------
template <int SMODE>
__global__ __launch_bounds__(384) void node_mfma_f(
    const float* __restrict__ in0, const float* __restrict__ in1,
    float* __restrict__ h_out,
    const unsigned short* __restrict__ Wh, const unsigned short* __restrict__ Wl,
    const float* __restrict__ bf, const float* __restrict__ bs,
    float2* __restrict__ D2, _Float16* __restrict__ Sh,
    float* __restrict__ agg_zero)
{
    __shared__ char zz[2 * 64 * 256];     // hi | lo, 256B rows
    const int tid = threadIdx.x;
    const int n0 = blockIdx.x * 64;
    char* const zh = zz;
    char* const zl = zz + 64 * 256;

    for (int u = tid; u < 64 * 23; u += 384) {
        int e = u / 23, q = u - e * 23;
        int node = n0 + e;
        if (node < N_NODES)
            ((float4*)(agg_zero + (size_t)node * NF))[q] = make_float4(0.f, 0.f, 0.f, 0.f);
    }

    for (int u = tid; u < 64 * 16; u += 384) {
        int e = u >> 4, c16 = u & 15;
        int node = n0 + e;
        unsigned short th[8], tl[8];
        if (c16 < 12 && node < N_NODES) {
            float v[8];
            load8f(in0 + (size_t)node * NF, c16, v);
            if (SMODE == 1) {
                float v1[8];
                load8f(in1 + (size_t)node * NF, c16, v1);
#pragma unroll
                for (int j = 0; j < 8; ++j) v[j] = fast_silu(v[j] + v1[j]);
                float* hr = h_out + (size_t)node * NF;
                if (c16 < 11) {
                    *(float4*)(hr + c16 * 8)     = make_float4(v[0], v[1], v[2], v[3]);
                    *(float4*)(hr + c16 * 8 + 4) = make_float4(v[4], v[5], v[6], v[7]);
                } else {
                    *(float4*)(hr + 88) = make_float4(v[0], v[1], v[2], v[3]);
                }
            }
#pragma unroll
            for (int j = 0; j < 8; ++j) {
                unsigned short hi = f2bf(v[j]);
                th[j] = hi;
                tl[j] = f2bf(v[j] - bf2f(hi));
            }
        } else {
#pragma unroll
            for (int j = 0; j < 8; ++j) { th[j] = 0; tl[j] = 0; }
        }
        int byte = (c16 * 16) ^ ((e & 7) << 4);
        *(uint4*)(zh + e * 256 + byte) = *(uint4*)th;
        *(uint4*)(zl + e * 256 + byte) = *(uint4*)tl;
    }
    __syncthreads();

    const int w = tid >> 6, lane = tid & 63, lr = lane & 15, lg = lane >> 4;
    const int col = w * 16 + lr;
    const float bfv = (col < NF) ? bf[col] : 0.f;
    const float bsv = (col < NF) ? bs[col] : 0.f;

    float keepD[4][4], keepS[4][4];

    for (int ntx = 0; ntx < 4; ++ntx) {
        const int nt = w + 6 * ntx;      // table t == ntx, col fixed
        f32x4 acc[4];
#pragma unroll
        for (int m = 0; m < 4; ++m) acc[m] = (f32x4){0.f, 0.f, 0.f, 0.f};

#pragma unroll
        for (int ks = 0; ks < 3; ++ks) {
            bf16x8 bh = *(const bf16x8*)(Wh + ((size_t)(ks * 24 + nt) * 64 + lane) * 8);
            bf16x8 bl = *(const bf16x8*)(Wl + ((size_t)(ks * 24 + nt) * 64 + lane) * 8);
#pragma unroll
            for (int m = 0; m < 4; ++m) {
                int row  = m * 16 + lr;
                int byte = (ks * 64 + lg * 16) ^ ((row & 7) << 4);
                bf16x8 ah = *(const bf16x8*)(zh + row * 256 + byte);
                bf16x8 al = *(const bf16x8*)(zl + row * 256 + byte);
                acc[m] = __builtin_amdgcn_mfma_f32_16x16x32_bf16(ah, bh, acc[m], 0, 0, 0);
                acc[m] = __builtin_amdgcn_mfma_f32_16x16x32_bf16(ah, bl, acc[m], 0, 0, 0);
                acc[m] = __builtin_amdgcn_mfma_f32_16x16x32_bf16(al, bh, acc[m], 0, 0, 0);
            }
        }

        if (col < NF) {
#pragma unroll
            for (int m = 0; m < 4; ++m) {
#pragma unroll
                for (int r = 0; r < 4; ++r) {
                    int node = n0 + m * 16 + lg * 4 + r;
                    if (ntx == 0) keepD[m][r] = acc[m][r] + bfv;        // Pf+bf
                    else if (ntx == 1) keepS[m][r] = acc[m][r];         // Qf
                    else if (ntx == 2) {                                // Ps+bs -> write D
                        if (node < N_NODES)
                            D2[(size_t)node * 96 + col] =
                                make_float2(keepD[m][r], acc[m][r] + bsv);
                    } else {                                            // Qs -> write S
                        if (node < N_NODES) {
                            f16x2 hv;
                            hv[0] = (_Float16)keepS[m][r];
                            hv[1] = (_Float16)acc[m][r];
                            *(f16x2*)(Sh + ((size_t)node * 96 + col) * 2) = hv;
                        }
                    }
                }
            }
        }
    }
}

// ---------------- edge kernel: 2 tiles/block, S+D prefetch before MFMA ----------------
template <bool EB>
__global__ __launch_bounds__(384) void edge_mfma9(
    const int* __restrict__ s_src, const int* __restrict__ s_dst,
    const int* __restrict__ perm, const float* __restrict__ ea,
    const _Float16* __restrict__ ebf,
    const _Float16* __restrict__ Wh, const _Float16* __restrict__ Wl,
    const float2* __restrict__ D2, const _Float16* __restrict__ Sh,
    float* __restrict__ agg, int nblk)
{
    __shared__ char zb[2][64 * 128];  // two 64-edge tiles, swizzled f16 rows
    __shared__ int sdst[128], ssrc[128], sperm[128];

    const int tid = threadIdx.x;
    const int bid = xcd_swz(blockIdx.x, nblk);
    const size_t e0 = (size_t)bid * 128;

    if (tid < 128) {
        ssrc[tid] = s_src[e0 + tid];
        sdst[tid] = s_dst[e0 + tid];
        if (!EB) sperm[tid] = perm[e0 + tid];
    }
    if (!EB) __syncthreads();

    // stage both tiles (128 edges x 8 16B-units)
    for (int u = tid; u < 128 * 8; u += 384) {
        int e = u >> 3, c16 = u & 7;
        uint4 v = make_uint4(0u, 0u, 0u, 0u);
        if (EB) {
            if (c16 < 6) v = *(const uint4*)(ebf + (e0 + e) * NEP + c16 * 8);
        } else {
            if (c16 < 6) {
                const float* ear = ea + (size_t)sperm[e] * EF;
                _Float16 t[8];
#pragma unroll
                for (int jj = 0; jj < 8; ++jj) {
                    int cc = c16 * 8 + jj;
                    t[jj] = (_Float16)((cc < EF) ? ear[cc] : 0.0f);
                }
                v = *(uint4*)t;
            }
        }
        int byte = (c16 * 16) ^ ((e & 7) << 4);
        *(uint4*)(zb[e >> 6] + (e & 63) * 128 + byte) = v;
    }
    __syncthreads();

    const int w = tid >> 6, lane = tid & 63, lr = lane & 15, lg = lane >> 4;
    const int c = w * 16 + lr;

#pragma unroll
    for (int t = 0; t < 2; ++t) {
        const int tb = t * 64;

        // prefetch: S rows (16 random half2) + run-start D rows (4 float2)
        f16x2 sv[4][4];
        float2 dv0[4];
#pragma unroll
        for (int m = 0; m < 4; ++m) {
#pragma unroll
            for (int r = 0; r < 4; ++r)
                sv[m][r] = *(const f16x2*)(Sh + ((size_t)ssrc[tb + m * 16 + lg * 4 + r] * 96 + c) * 2);
            dv0[m] = D2[(size_t)sdst[tb + m * 16 + lg * 4] * 96 + c];
        }

        f32x4 accF[4], accS[4];
#pragma unroll
        for (int m = 0; m < 4; ++m) {
            accF[m] = (f32x4){0.f, 0.f, 0.f, 0.f};
            accS[m] = (f32x4){0.f, 0.f, 0.f, 0.f};
        }

#pragma unroll
        for (int ks = 0; ks < 2; ++ks) {
            f16x8 bFh = *(const f16x8*)(Wh + ((size_t)(ks * 12 + w)     * 64 + lane) * 8);
            f16x8 bFl = *(const f16x8*)(Wl + ((size_t)(ks * 12 + w)     * 64 + lane) * 8);
            f16x8 bSh = *(const f16x8*)(Wh + ((size_t)(ks * 12 + w + 6) * 64 + lane) * 8);
            f16x8 bSl = *(const f16x8*)(Wl + ((size_t)(ks * 12 + w + 6) * 64 + lane) * 8);
#pragma unroll
            for (int m = 0; m < 4; ++m) {
                int row  = m * 16 + lr;
                int byte = (ks * 64 + lg * 16) ^ ((row & 7) << 4);
                f16x8 a = *(const f16x8*)(zb[t] + row * 128 + byte);
                accF[m] = __builtin_amdgcn_mfma_f32_16x16x32_f16(a, bFh, accF[m], 0, 0, 0);
                accF[m] = __builtin_amdgcn_mfma_f32_16x16x32_f16(a, bFl, accF[m], 0, 0, 0);
                accS[m] = __builtin_amdgcn_mfma_f32_16x16x32_f16(a, bSh, accS[m], 0, 0, 0);
                accS[m] = __builtin_amdgcn_mfma_f32_16x16x32_f16(a, bSl, accS[m], 0, 0, 0);
            }
        }

        if (c < NF) {
#pragma unroll
            for (int m = 0; m < 4; ++m) {
                const int eb0 = tb + m * 16 + lg * 4;
                int prev = sdst[eb0];
                float2 dv = dv0[m];
                float accum = 0.f;
#pragma unroll
                for (int r = 0; r < 4; ++r) {
                    int dst = sdst[eb0 + r];
                    if (dst != prev) {
                        atomicAdd(&agg[(size_t)prev * NF + c], accum);
                        accum = 0.f;
                        prev = dst;
                        dv = D2[(size_t)dst * 96 + c];
                    }
                    float f = accF[m][r] + dv.x + (float)sv[m][r][0];
                    float s = accS[m][r] + dv.y + (float)sv[m][r][1];
                    accum += fast_sigmoid(f) * fast_softplus(s);
                }
                atomicAdd(&agg[(size_t)prev * NF + c], accum);
            }
        }
    }
}

// ---------------- fused fc1 via split-bf16 MFMA ----------------
template <int SMODE, bool POOL>
__global__ __launch_bounds__(384) void fc_mfma_f(
    const float* __restrict__ in0, const float* __restrict__ in1,
    const unsigned short* __restrict__ Wh, const unsigned short* __restrict__ Wl,
    const float* __restrict__ b, float* __restrict__ outp)
{
    __shared__ char zz[2 * 64 * 256];
    const int tid = threadIdx.x;
    const int n0 = blockIdx.x * 64;
    char* const zh = zz;
    char* const zl = zz + 64 * 256;

    for (int u = tid; u < 64 * 16; u += 384) {
        int e = u >> 4, c16 = u & 15;
        int node = n0 + e;
        unsigned short th[8], tl[8];
        if (c16 < 12 && node < N_NODES) {
            float v[8];
            load8f(in0 + (size_t)node * NF, c16, v);
            if (SMODE == 1) {
                float v1[8];
                load8f(in1 + (size_t)node * NF, c16, v1);
#pragma unroll
                for (int j = 0; j < 8; ++j) v[j] = fast_silu(v[j] + v1[j]);
            }
#pragma unroll
            for (int j = 0; j < 8; ++j) {
                unsigned short hi = f2bf(v[j]);
                th[j] = hi;
                tl[j] = f2bf(v[j] - bf2f(hi));
            }
        } else {
#pragma unroll
            for (int j = 0; j < 8; ++j) { th[j] = 0; tl[j] = 0; }
        }
        int byte = (c16 * 16) ^ ((e & 7) << 4);
        *(uint4*)(zh + e * 256 + byte) = *(uint4*)th;
        *(uint4*)(zl + e * 256 + byte) = *(uint4*)tl;
    }
    __syncthreads();

    const int w = tid >> 6, lane = tid & 63, lr = lane & 15, lg = lane >> 4;
    const int col = w * 16 + lr;
    const float bv = (col < NF) ? b[col] : 0.f;

    f32x4 acc[4];
#pragma unroll
    for (int m = 0; m < 4; ++m) acc[m] = (f32x4){0.f, 0.f, 0.f, 0.f};

#pragma unroll
    for (int ks = 0; ks < 3; ++ks) {
        bf16x8 bh = *(const bf16x8*)(Wh + ((size_t)(ks * 6 + w) * 64 + lane) * 8);
        bf16x8 bl = *(const bf16x8*)(Wl + ((size_t)(ks * 6 + w) * 64 + lane) * 8);
#pragma unroll
        for (int m = 0; m < 4; ++m) {
            int row  = m * 16 + lr;
            int byte = (ks * 64 + lg * 16) ^ ((row & 7) << 4);
            bf16x8 ah = *(const bf16x8*)(zh + row * 256 + byte);
            bf16x8 al = *(const bf16x8*)(zl + row * 256 + byte);
            acc[m] = __builtin_amdgcn_mfma_f32_16x16x32_bf16(ah, bh, acc[m], 0, 0, 0);
            acc[m] = __builtin_amdgcn_mfma_f32_16x16x32_bf16(ah, bl, acc[m], 0, 0, 0);
            acc[m] = __builtin_amdgcn_mfma_f32_16x16x32_bf16(al, bh, acc[m], 0, 0, 0);
        }
    }

    if (POOL) {
        float psum = 0.f;
#pragma unroll
        for (int m = 0; m < 4; ++m)
#pragma unroll
            for (int r = 0; r < 4; ++r) {
                int node = n0 + m * 16 + lg * 4 + r;
                if (node < N_NODES && col < NF)
                    psum += fast_silu(acc[m][r] + bv);
            }
        psum += __shfl_down(psum, 32);
        psum += __shfl_down(psum, 16);
        if (lg == 0 && col < NF) atomicAdd(&outp[col], psum);
    } else {
#pragma unroll
        for (int m = 0; m < 4; ++m)
#pragma unroll
            for (int r = 0; r < 4; ++r) {
                int node = n0 + m * 16 + lg * 4 + r;
                if (node < N_NODES && col < NF)
                    outp[(size_t)node * NF + col] = fast_silu(acc[m][r] + bv);
            }
    }
}

// ---------------- split MLP head ----------------
__global__ __launch_bounds__(128) void mlp_a(const float* __restrict__ pooled,
                                             const float* __restrict__ glob,
                                             const float* __restrict__ W2,
                                             const float* __restrict__ b2,
                                             float* __restrict__ g1)
{
    __shared__ float vin[NF + GF];
    const int t = threadIdx.x;
    for (int i = t; i < NF + GF; i += 128)
        vin[i] = (i < NF) ? pooled[i] * (1.0f / (float)N_NODES) : glob[i - NF];
    __syncthreads();
    const int col = blockIdx.x * 128 + t;
    float a = b2[col];
    for (int k = 0; k < NF + GF; ++k) a = fmaf(vin[k], W2[k * 1024 + col], a);
    g1[col] = fast_silu(a);
}

__global__ __launch_bounds__(128) void mlp_b(const float* __restrict__ g1,
                                             const float* __restrict__ W3,
                                             const float* __restrict__ b3,
                                             float* __restrict__ g2)
{
    __shared__ float vin[1024];
    const int t = threadIdx.x;
    for (int i = t; i < 1024; i += 128) vin[i] = g1[i];
    __syncthreads();
    const int col = blockIdx.x * 128 + t;
    float a = b3[col];
    for (int k = 0; k < 1024; ++k) a = fmaf(vin[k], W3[k * 512 + col], a);
    g2[col] = fast_silu(a);
}

__global__ __launch_bounds__(512) void mlp_c(const float* __restrict__ g2,
    const float* __restrict__ W4, const float* __restrict__ b4,
    const float* __restrict__ W5, const float* __restrict__ b5,
    const float* __restrict__ W6, const float* __restrict__ b6,
    const float* __restrict__ W7, const float* __restrict__ b7,
    float* __restrict__ out)
{
    __shared__ float va[512], vb[256];
    const int t = threadIdx.x;
    va[t] = g2[t];
    __syncthreads();

    if (t < 256) { // fc4: 512 -> 256
        float a = b4[t];
        for (int k = 0; k < 512; ++k) a = fmaf(va[k], W4[k * 256 + t], a);
        vb[t] = fast_silu(a);
    }
    __syncthreads();
    if (t < 128) { // fc5: 256 -> 128
        float a = b5[t];
        for (int k = 0; k < 256; ++k) a = fmaf(vb[k], W5[k * 128 + t], a);
        va[t] = fast_silu(a);
    }
    __syncthreads();
    if (t < 64) { // fc6: 128 -> 64
        float a = b6[t];
        for (int k = 0; k < 128; ++k) a = fmaf(va[k], W6[k * 64 + t], a);
        vb[t] = fast_silu(a);
    }
    __syncthreads();
    if (t < 64) { // fc7: 64 -> 1
        float p = vb[t] * W7[t];
        for (int off = 32; off; off >>= 1) p += __shfl_down(p, off);
        if (t == 0) out[0] = p + b7[0];
    }
}

// ---------------- launch ----------------
extern "C" void kernel_launch(void* const* d_in, const int* in_sizes, int n_in,
                              void* d_out, int out_size, void* d_ws, size_t ws_size,
                              hipStream_t stream)
{
    (void)in_sizes; (void)n_in; (void)out_size;

    const float* x    = (const float*)d_in[0];
    const int*   ei   = (const int*)d_in[1];
    const float* ea   = (const float*)d_in[2];
    const float* glob = (const float*)d_in[3];
    const float* cWf[3] = {(const float*)d_in[5],  (const float*)d_in[9],  (const float*)d_in[13]};
    const float* cbf[3] = {(const float*)d_in[6],  (const float*)d_in[10], (const float*)d_in[14]};
    const float* cWs[3] = {(const float*)d_in[7],  (const float*)d_in[11], (const float*)d_in[15]};
    const float* cbs[3] = {(const float*)d_in[8],  (const float*)d_in[12], (const float*)d_in[16]};
    const float* fc1W = (const float*)d_in[17]; const float* fc1b = (const float*)d_in[18];
    const float* W2 = (const float*)d_in[19];   const float* b2 = (const float*)d_in[20];
    const float* W3 = (const float*)d_in[21];   const float* b3 = (const float*)d_in[22];
    const float* W4 = (const float*)d_in[23];   const float* b4 = (const float*)d_in[24];
    const float* W5 = (const float*)d_in[25];   const float* b5 = (const float*)d_in[26];
    const float* W6 = (const float*)d_in[27];   const float* b6 = (const float*)d_in[28];
    const float* W7 = (const float*)d_in[29];   const float* b7 = (const float*)d_in[30];
    float* out = (float*)d_out;

    const size_t H = (size_t)N_NODES * NF;
    float* h1   = (float*)d_ws;                              // fp32 node state
    float* h2   = h1 + H;
    float* aggA = h2 + H;
    float* aggB = aggA + H;
    float* pooled = aggB + H;                                // 128
    float* g1 = pooled + 128;                                // 1024
    float* g2 = g1 + 1024;                                   // 512
    unsigned short* WcNh = (unsigned short*)(g2 + 512);      // 3*36864 bf16
    unsigned short* WcNl = WcNh + 3 * (size_t)36864;
    unsigned short* WcFh = WcNl + 3 * (size_t)36864;         // 9216 bf16
    unsigned short* WcFl = WcFh + (size_t)WCF_ELEMS;
    _Float16* WcEh = (_Float16*)(WcFl + (size_t)WCF_ELEMS);  // 3*12288 f16
    _Float16* WcEl = WcEh + 3 * (size_t)12288;
    float2* D2 = (float2*)(WcEl + 3 * (size_t)12288);        // N*96 float2
    _Float16* Sh = (_Float16*)(D2 + (size_t)N_NODES * 96);   // N*96 f16x2
    int* bins   = (int*)(Sh + (size_t)2 * N_NODES * 96);
    int* cursor = bins + N_NODES;
    int* perm   = cursor + N_NODES;
    int* invp   = perm + N_EDGES;
    int* s_src  = invp + N_EDGES;
    int* s_dst  = s_src + N_EDGES;
    _Float16* ebf = (_Float16*)(s_dst + N_EDGES);            // E*48 f16 (sorted)
    const size_t need_full = (size_t)((char*)(ebf + (size_t)N_EDGES * NEP) - (char*)d_ws);
    const bool use_eb = ws_size >= need_full;

    const int nEdgeBlocks = N_EDGES / 128;                   // 6250 (2 tiles each)
    const int nNodeBlocks = (N_NODES + 63) / 64;             // 782

    // one-time: sort edges by dst, scatter ea to sorted f16, convert weights
    hipMemsetAsync(bins, 0, N_NODES * sizeof(int), stream);
    hist_kernel<<<(N_EDGES + 255) / 256, 256, 0, stream>>>(ei, bins);
    scan_kernel<<<1, 1024, 0, stream>>>(bins, cursor);
    place_kernel<<<(N_EDGES + 255) / 256, 256, 0, stream>>>(ei, cursor, perm, invp, s_src, s_dst);
    if (use_eb)
        permute_ea16s<<<(int)(((long)N_EDGES * NEP + 255) / 256), 256, 0, stream>>>(ea, invp, ebf);
    convert_all<<<612, 256, 0, stream>>>(cWf[0], cWs[0], cWf[1], cWs[1], cWf[2], cWs[2],
                                         fc1W, WcNh, WcNl, WcEh, WcEl, WcFh, WcFl);

    // conv layers (fused: silu+residual+stage+agg-zero inside node_mfma_f)
    node_mfma_f<0><<<nNodeBlocks, 384, 0, stream>>>(x, nullptr, nullptr,
        WcNh, WcNl, cbf[0], cbs[0], D2, Sh, aggA);
    if (use_eb)
        edge_mfma9<true><<<nEdgeBlocks, 384, 0, stream>>>(s_src, s_dst, perm, ea, ebf,
            WcEh, WcEl, D2, Sh, aggA, nEdgeBlocks);
    else
        edge_mfma9<false><<<nEdgeBlocks, 384, 0, stream>>>(s_src, s_dst, perm, ea, ebf,
            WcEh, WcEl, D2, Sh, aggA, nEdgeBlocks);

    node_mfma_f<1><<<nNodeBlocks, 384, 0, stream>>>(x, aggA, h1,
        WcNh + (size_t)36864, WcNl + (size_t)36864, cbf[1], cbs[1], D2, Sh, aggB);
    if (use_eb)
        edge_mfma9<true><<<nEdgeBlocks, 384, 0, stream>>>(s_src, s_dst, perm, ea, ebf,
            WcEh + (size_t)12288, WcEl + (size_t)12288, D2, Sh, aggB, nEdgeBlocks);
    else
        edge_mfma9<false><<<nEdgeBlocks, 384, 0, stream>>>(s_src, s_dst, perm, ea, ebf,
            WcEh + (size_t)12288, WcEl + (size_t)12288, D2, Sh, aggB, nEdgeBlocks);

    node_mfma_f<1><<<nNodeBlocks, 384, 0, stream>>>(h1, aggB, h2,
        WcNh + (size_t)2 * 36864, WcNl + (size_t)2 * 36864, cbf[2], cbs[2], D2, Sh, aggA);
    if (use_eb)
        edge_mfma9<true><<<nEdgeBlocks, 384, 0, stream>>>(s_src, s_dst, perm, ea, ebf,
            WcEh + (size_t)2 * 12288, WcEl + (size_t)2 * 12288, D2, Sh, aggA, nEdgeBlocks);
    else
        edge_mfma9<false><<<nEdgeBlocks, 384, 0, stream>>>(s_src, s_dst, perm, ea, ebf,
            WcEh + (size_t)2 * 12288, WcEl + (size_t)2 * 12288, D2, Sh, aggA, nEdgeBlocks);

    // fc1 #1: stage silu(h2 + aggA), write fp32 -> aggB
    fc_mfma_f<1, false><<<nNodeBlocks, 384, 0, stream>>>(h2, aggA, WcFh, WcFl, fc1b, aggB);
    // fc1 #2: stage aggB, fused mean-pool into pooled
    hipMemsetAsync(pooled, 0, NF * sizeof(float), stream);
    fc_mfma_f<0, true><<<nNodeBlocks, 384, 0, stream>>>(aggB, nullptr, WcFh, WcFl, fc1b, pooled);

    // MLP head (split)
    mlp_a<<<8, 128, 0, stream>>>(pooled, glob, W2, b2, g1);
    mlp_b<<<4, 128, 0, stream>>>(g1, W3, b3, g2);
    mlp_c<<<1, 512, 0, stream>>>(g2, W4, b4, W5, b5, W6, b6, W7, b7, out);
}

// Round 13
// 1283.407 us; speedup vs baseline: 1.0543x; 1.0543x over previous
//
#include <hip/hip_runtime.h>
#include <math.h>

// ---------------- problem constants ----------------
#define N_NODES 50000
#define N_EDGES 800000
#define NF 92           // node features
#define EF 41           // edge features
#define GF 180          // global attr
#define NEP 48          // padded f16 edge_attr row (dst-sorted)

#define WCN_ELEMS (3 * 24 * 64 * 8)   // node-GEMM weights per layer (bf16 hi/lo)
#define WCE_ELEMS (2 * 12 * 64 * 8)   // edge-GEMM weights per layer (f16 hi/lo)
#define WCF_ELEMS (3 * 6 * 64 * 8)    // fc1 weights (bf16 hi/lo)

typedef __attribute__((ext_vector_type(8))) short bf16x8;
typedef __attribute__((ext_vector_type(8))) _Float16 f16x8;
typedef __attribute__((ext_vector_type(2))) _Float16 f16x2;
typedef __attribute__((ext_vector_type(4))) float f32x4;

#define L2E 1.44269504f
#define LN2 0.69314718f

__device__ __forceinline__ float fast_sigmoid(float x) {
    return __builtin_amdgcn_rcpf(1.0f + __builtin_amdgcn_exp2f(-x * L2E));
}
__device__ __forceinline__ float fast_softplus(float x) {
    float t = __builtin_amdgcn_exp2f(-fabsf(x) * L2E);
    return fmaxf(x, 0.0f) + __builtin_amdgcn_logf(1.0f + t) * LN2;
}
__device__ __forceinline__ float fast_silu(float x) { return x * fast_sigmoid(x); }

__device__ __forceinline__ unsigned short f2bf(float x) {
    union { float f; unsigned u; } v; v.f = x;
    unsigned r = v.u + 0x7FFF + ((v.u >> 16) & 1);   // RNE
    return (unsigned short)(r >> 16);
}
__device__ __forceinline__ float bf2f(unsigned short h) {
    union { unsigned u; float f; } v; v.u = ((unsigned)h) << 16; return v.f;
}

// bijective XCD-aware block swizzle (m204 variant)
__device__ __forceinline__ int xcd_swz(int bid, int nwg) {
    int q = nwg >> 3, r = nwg & 7;
    int xcd = bid & 7, idx = bid >> 3;
    return (xcd < r ? xcd * (q + 1) : r * (q + 1) + (xcd - r) * q) + idx;
}

// load 8 fp32 from a 92-float row at cols [c16*8, c16*8+8), zero-padded past 91
__device__ __forceinline__ void load8f(const float* __restrict__ rowp, int c16, float v[8]) {
    if (c16 < 11) {
        float4 a = *(const float4*)(rowp + c16 * 8);
        float4 b = *(const float4*)(rowp + c16 * 8 + 4);
        v[0]=a.x; v[1]=a.y; v[2]=a.z; v[3]=a.w; v[4]=b.x; v[5]=b.y; v[6]=b.z; v[7]=b.w;
    } else {
        float4 a = *(const float4*)(rowp + 88);
        v[0]=a.x; v[1]=a.y; v[2]=a.z; v[3]=a.w; v[4]=0.f; v[5]=0.f; v[6]=0.f; v[7]=0.f;
    }
}

// ---------------- sort infra: counting sort of edges by dst ----------------
__global__ __launch_bounds__(256) void hist_kernel(const int* __restrict__ ei,
                                                   int* __restrict__ bins)
{
    int e = blockIdx.x * 256 + threadIdx.x;
    if (e < N_EDGES) atomicAdd(&bins[ei[N_EDGES + e]], 1);
}

__global__ __launch_bounds__(1024) void scan_kernel(const int* __restrict__ bins,
                                                    int* __restrict__ cursor)
{
    __shared__ int tot[1024];
    const int t = threadIdx.x;
    const int C = (N_NODES + 1023) / 1024;
    const int i0 = t * C, i1 = min(i0 + C, N_NODES);
    int s = 0;
    for (int i = i0; i < i1; ++i) s += bins[i];
    tot[t] = s;
    __syncthreads();
    for (int off = 1; off < 1024; off <<= 1) {
        int v = (t >= off) ? tot[t - off] : 0;
        __syncthreads();
        tot[t] += v;
        __syncthreads();
    }
    int run = tot[t] - s;   // exclusive base
    for (int i = i0; i < i1; ++i) { cursor[i] = run; run += bins[i]; }
}

__global__ __launch_bounds__(256) void place_kernel(const int* __restrict__ ei,
                                                    int* __restrict__ cursor,
                                                    int* __restrict__ perm,
                                                    int* __restrict__ invp,
                                                    int* __restrict__ s_src,
                                                    int* __restrict__ s_dst)
{
    int e = blockIdx.x * 256 + threadIdx.x;
    if (e < N_EDGES) {
        int d = ei[N_EDGES + e];
        int pos = atomicAdd(&cursor[d], 1);
        perm[pos] = e;
        invp[e] = pos;
        s_dst[pos] = d;
        s_src[pos] = ei[e];
    }
}

// ---------------- one-time: scatter ea into dst-sorted f16 rows (coalesced read) ----------------
__global__ __launch_bounds__(256) void permute_ea16s(const float* __restrict__ ea,
                                                     const int* __restrict__ invp,
                                                     _Float16* __restrict__ ebf)
{
    long i = (long)blockIdx.x * 256 + threadIdx.x;
    if (i >= (long)N_EDGES * NEP) return;
    long e = i / NEP; int c = (int)(i - e * NEP);
    float v = (c < EF) ? ea[e * EF + c] : 0.0f;
    ebf[(size_t)invp[e] * NEP + c] = (_Float16)v;
}

// ---------------- merged weight conversion (all layers, node+edge+fc) ----------------
__global__ __launch_bounds__(256) void convert_all(
    const float* __restrict__ Wf0, const float* __restrict__ Ws0,
    const float* __restrict__ Wf1, const float* __restrict__ Ws1,
    const float* __restrict__ Wf2, const float* __restrict__ Ws2,
    const float* __restrict__ fc1W,
    unsigned short* __restrict__ WcNh, unsigned short* __restrict__ WcNl,
    _Float16* __restrict__ WcEh, _Float16* __restrict__ WcEl,
    unsigned short* __restrict__ WcFh, unsigned short* __restrict__ WcFl)
{
    const int bid = blockIdx.x;
    if (bid < 432) {
        int l = bid / 144;
        int idx = (bid - l * 144) * 256 + threadIdx.x;
        if (idx >= 36864) return;
        const float* Wf = (l == 0) ? Wf0 : (l == 1) ? Wf1 : Wf2;
        const float* Ws = (l == 0) ? Ws0 : (l == 1) ? Ws1 : Ws2;
        int j    = idx & 7;
        int lane = (idx >> 3) & 63;
        int nt   = (idx >> 9) % 24;
        int ks   = idx / (24 * 512);
        int k = ks * 32 + ((lane >> 4) * 8) + j;
        int n = nt * 16 + (lane & 15);
        int t = n / 96, col = n % 96;
        float val = 0.f;
        if (k < 92 && col < 92) {
            const float* W = (t < 2) ? Wf : Ws;
            int rowoff = (t & 1) ? 92 : 0;
            val = W[(rowoff + k) * NF + col];
        }
        unsigned short hi = f2bf(val);
        size_t o = (size_t)l * 36864 + idx;
        WcNh[o] = hi;
        WcNl[o] = f2bf(val - bf2f(hi));
    } else if (bid < 576) {
        int b2 = bid - 432;
        int l = b2 / 48;
        int idx = (b2 - l * 48) * 256 + threadIdx.x;
        if (idx >= 12288) return;
        const float* Wf = (l == 0) ? Wf0 : (l == 1) ? Wf1 : Wf2;
        const float* Ws = (l == 0) ? Ws0 : (l == 1) ? Ws1 : Ws2;
        int j    = idx & 7;
        int lane = (idx >> 3) & 63;
        int nt   = (idx >> 9) % 12;
        int ks   = idx / (12 * 512);
        int k = ks * 32 + ((lane >> 4) * 8) + j;
        int n = nt * 16 + (lane & 15);
        float val = 0.f;
        if (k < EF) {
            if (n < 92)                  val = Wf[(184 + k) * NF + n];
            else if (n >= 96 && n < 188) val = Ws[(184 + k) * NF + (n - 96)];
        }
        _Float16 hi = (_Float16)val;
        size_t o = (size_t)l * 12288 + idx;
        WcEh[o] = hi;
        WcEl[o] = (_Float16)(val - (float)hi);
    } else {
        int idx = (bid - 576) * 256 + threadIdx.x;
        if (idx >= WCF_ELEMS) return;
        int j    = idx & 7;
        int lane = (idx >> 3) & 63;
        int nt   = (idx >> 9) % 6;
        int ks   = idx / (6 * 512);
        int k = ks * 32 + ((lane >> 4) * 8) + j;
        int n = nt * 16 + (lane & 15);
        float val = (k < 92 && n < 92) ? fc1W[k * NF + n] : 0.f;
        unsigned short hi = f2bf(val);
        WcFh[idx] = hi;
        WcFl[idx] = f2bf(val - bf2f(hi));
    }
}

// ---------------- fused node GEMM ----------------
template <int SMODE>
__global__ __launch_bounds__(384) void node_mfma_f(
    const float* __restrict__ in0, const float* __restrict__ in1,
    float* __restrict__ h_out,
    const unsigned short* __restrict__ Wh, const unsigned short* __restrict__ Wl,
    const float* __restrict__ bf, const float* __restrict__ bs,
    float2* __restrict__ D2, _Float16* __restrict__ Sh,
    float* __restrict__ agg_zero)
{
    __shared__ char zz[2 * 64 * 256];     // hi | lo, 256B rows
    const int tid = threadIdx.x;
    const int n0 = blockIdx.x * 64;
    char* const zh = zz;
    char* const zl = zz + 64 * 256;

    for (int u = tid; u < 64 * 23; u += 384) {
        int e = u / 23, q = u - e * 23;
        int node = n0 + e;
        if (node < N_NODES)
            ((float4*)(agg_zero + (size_t)node * NF))[q] = make_float4(0.f, 0.f, 0.f, 0.f);
    }

    for (int u = tid; u < 64 * 16; u += 384) {
        int e = u >> 4, c16 = u & 15;
        int node = n0 + e;
        unsigned short th[8], tl[8];
        if (c16 < 12 && node < N_NODES) {
            float v[8];
            load8f(in0 + (size_t)node * NF, c16, v);
            if (SMODE == 1) {
                float v1[8];
                load8f(in1 + (size_t)node * NF, c16, v1);
#pragma unroll
                for (int j = 0; j < 8; ++j) v[j] = fast_silu(v[j] + v1[j]);
                float* hr = h_out + (size_t)node * NF;
                if (c16 < 11) {
                    *(float4*)(hr + c16 * 8)     = make_float4(v[0], v[1], v[2], v[3]);
                    *(float4*)(hr + c16 * 8 + 4) = make_float4(v[4], v[5], v[6], v[7]);
                } else {
                    *(float4*)(hr + 88) = make_float4(v[0], v[1], v[2], v[3]);
                }
            }
#pragma unroll
            for (int j = 0; j < 8; ++j) {
                unsigned short hi = f2bf(v[j]);
                th[j] = hi;
                tl[j] = f2bf(v[j] - bf2f(hi));
            }
        } else {
#pragma unroll
            for (int j = 0; j < 8; ++j) { th[j] = 0; tl[j] = 0; }
        }
        int byte = (c16 * 16) ^ ((e & 7) << 4);
        *(uint4*)(zh + e * 256 + byte) = *(uint4*)th;
        *(uint4*)(zl + e * 256 + byte) = *(uint4*)tl;
    }
    __syncthreads();

    const int w = tid >> 6, lane = tid & 63, lr = lane & 15, lg = lane >> 4;
    const int col = w * 16 + lr;
    const float bfv = (col < NF) ? bf[col] : 0.f;
    const float bsv = (col < NF) ? bs[col] : 0.f;

    float keepD[4][4], keepS[4][4];

    for (int ntx = 0; ntx < 4; ++ntx) {
        const int nt = w + 6 * ntx;      // table t == ntx, col fixed
        f32x4 acc[4];
#pragma unroll
        for (int m = 0; m < 4; ++m) acc[m] = (f32x4){0.f, 0.f, 0.f, 0.f};

#pragma unroll
        for (int ks = 0; ks < 3; ++ks) {
            bf16x8 bh = *(const bf16x8*)(Wh + ((size_t)(ks * 24 + nt) * 64 + lane) * 8);
            bf16x8 bl = *(const bf16x8*)(Wl + ((size_t)(ks * 24 + nt) * 64 + lane) * 8);
#pragma unroll
            for (int m = 0; m < 4; ++m) {
                int row  = m * 16 + lr;
                int byte = (ks * 64 + lg * 16) ^ ((row & 7) << 4);
                bf16x8 ah = *(const bf16x8*)(zh + row * 256 + byte);
                bf16x8 al = *(const bf16x8*)(zl + row * 256 + byte);
                acc[m] = __builtin_amdgcn_mfma_f32_16x16x32_bf16(ah, bh, acc[m], 0, 0, 0);
                acc[m] = __builtin_amdgcn_mfma_f32_16x16x32_bf16(ah, bl, acc[m], 0, 0, 0);
                acc[m] = __builtin_amdgcn_mfma_f32_16x16x32_bf16(al, bh, acc[m], 0, 0, 0);
            }
        }

        if (col < NF) {
#pragma unroll
            for (int m = 0; m < 4; ++m) {
#pragma unroll
                for (int r = 0; r < 4; ++r) {
                    int node = n0 + m * 16 + lg * 4 + r;
                    if (ntx == 0) keepD[m][r] = acc[m][r] + bfv;        // Pf+bf
                    else if (ntx == 1) keepS[m][r] = acc[m][r];         // Qf
                    else if (ntx == 2) {                                // Ps+bs -> write D
                        if (node < N_NODES)
                            D2[(size_t)node * 96 + col] =
                                make_float2(keepD[m][r], acc[m][r] + bsv);
                    } else {                                            // Qs -> write S
                        if (node < N_NODES) {
                            f16x2 hv;
                            hv[0] = (_Float16)keepS[m][r];
                            hv[1] = (_Float16)acc[m][r];
                            *(f16x2*)(Sh + ((size_t)node * 96 + col) * 2) = hv;
                        }
                    }
                }
            }
        }
    }
}

// ---------------- edge kernel: round-10 structure + D2 run-start prefetch ----------------
template <bool EB>
__global__ __launch_bounds__(384) void edge_mfma10(
    const int* __restrict__ s_src, const int* __restrict__ s_dst,
    const int* __restrict__ perm, const float* __restrict__ ea,
    const _Float16* __restrict__ ebf,
    const _Float16* __restrict__ Wh, const _Float16* __restrict__ Wl,
    const float2* __restrict__ D2, const _Float16* __restrict__ Sh,
    float* __restrict__ agg, int nblk)
{
    __shared__ char zb[64 * 128];     // z: 64 edges x 64 f16 (128B rows), swizzled
    __shared__ int sdst[64], ssrc[64], sperm[64];

    const int tid = threadIdx.x;
    const int bid = xcd_swz(blockIdx.x, nblk);
    const size_t e0 = (size_t)bid * 64;

    if (tid < 64) {
        ssrc[tid] = s_src[e0 + tid];
        sdst[tid] = s_dst[e0 + tid];
        if (!EB) sperm[tid] = perm[e0 + tid];
    }
    if (!EB) __syncthreads();

    for (int u = tid; u < 64 * 8; u += 384) {
        int e = u >> 3, c16 = u & 7;
        uint4 v = make_uint4(0u, 0u, 0u, 0u);
        if (EB) {
            if (c16 < 6) v = *(const uint4*)(ebf + (e0 + e) * NEP + c16 * 8);
        } else {
            if (c16 < 6) {
                const float* ear = ea + (size_t)sperm[e] * EF;
                _Float16 t[8];
#pragma unroll
                for (int jj = 0; jj < 8; ++jj) {
                    int cc = c16 * 8 + jj;
                    t[jj] = (_Float16)((cc < EF) ? ear[cc] : 0.0f);
                }
                v = *(uint4*)t;
            }
        }
        int byte = (c16 * 16) ^ ((e & 7) << 4);
        *(uint4*)(zb + e * 128 + byte) = v;
    }
    __syncthreads();

    const int w = tid >> 6, lane = tid & 63, lr = lane & 15, lg = lane >> 4;
    const int c = w * 16 + lr;

    // prefetch BEFORE MFMA: 16 random S half2 + 4 run-start D float2 —
    // latency hides under the matrix cluster
    f16x2 sv[4][4];
    float2 dv0[4];
#pragma unroll
    for (int m = 0; m < 4; ++m) {
#pragma unroll
        for (int r = 0; r < 4; ++r)
            sv[m][r] = *(const f16x2*)(Sh + ((size_t)ssrc[m * 16 + lg * 4 + r] * 96 + c) * 2);
        dv0[m] = D2[(size_t)sdst[m * 16 + lg * 4] * 96 + c];
    }

    f32x4 accF[4], accS[4];
#pragma unroll
    for (int m = 0; m < 4; ++m) {
        accF[m] = (f32x4){0.f, 0.f, 0.f, 0.f};
        accS[m] = (f32x4){0.f, 0.f, 0.f, 0.f};
    }

#pragma unroll
    for (int ks = 0; ks < 2; ++ks) {
        f16x8 bFh = *(const f16x8*)(Wh + ((size_t)(ks * 12 + w)     * 64 + lane) * 8);
        f16x8 bFl = *(const f16x8*)(Wl + ((size_t)(ks * 12 + w)     * 64 + lane) * 8);
        f16x8 bSh = *(const f16x8*)(Wh + ((size_t)(ks * 12 + w + 6) * 64 + lane) * 8);
        f16x8 bSl = *(const f16x8*)(Wl + ((size_t)(ks * 12 + w + 6) * 64 + lane) * 8);
#pragma unroll
        for (int m = 0; m < 4; ++m) {
            int row  = m * 16 + lr;
            int byte = (ks * 64 + lg * 16) ^ ((row & 7) << 4);
            f16x8 a = *(const f16x8*)(zb + row * 128 + byte);
            accF[m] = __builtin_amdgcn_mfma_f32_16x16x32_f16(a, bFh, accF[m], 0, 0, 0);
            accF[m] = __builtin_amdgcn_mfma_f32_16x16x32_f16(a, bFl, accF[m], 0, 0, 0);
            accS[m] = __builtin_amdgcn_mfma_f32_16x16x32_f16(a, bSh, accS[m], 0, 0, 0);
            accS[m] = __builtin_amdgcn_mfma_f32_16x16x32_f16(a, bSl, accS[m], 0, 0, 0);
        }
    }

    if (c < NF) {
#pragma unroll
        for (int m = 0; m < 4; ++m) {
            const int eb0 = m * 16 + lg * 4;
            int prev = sdst[eb0];
            float2 dv = dv0[m];
            float accum = 0.f;
#pragma unroll
            for (int r = 0; r < 4; ++r) {
                int dst = sdst[eb0 + r];
                if (dst != prev) {
                    atomicAdd(&agg[(size_t)prev * NF + c], accum);
                    accum = 0.f;
                    prev = dst;
                    dv = D2[(size_t)dst * 96 + c];
                }
                float f = accF[m][r] + dv.x + (float)sv[m][r][0];
                float s = accS[m][r] + dv.y + (float)sv[m][r][1];
                accum += fast_sigmoid(f) * fast_softplus(s);
            }
            atomicAdd(&agg[(size_t)prev * NF + c], accum);
        }
    }
}

// ---------------- fused fc1 via split-bf16 MFMA ----------------
template <int SMODE, bool POOL>
__global__ __launch_bounds__(384) void fc_mfma_f(
    const float* __restrict__ in0, const float* __restrict__ in1,
    const unsigned short* __restrict__ Wh, const unsigned short* __restrict__ Wl,
    const float* __restrict__ b, float* __restrict__ outp)
{
    __shared__ char zz[2 * 64 * 256];
    const int tid = threadIdx.x;
    const int n0 = blockIdx.x * 64;
    char* const zh = zz;
    char* const zl = zz + 64 * 256;

    for (int u = tid; u < 64 * 16; u += 384) {
        int e = u >> 4, c16 = u & 15;
        int node = n0 + e;
        unsigned short th[8], tl[8];
        if (c16 < 12 && node < N_NODES) {
            float v[8];
            load8f(in0 + (size_t)node * NF, c16, v);
            if (SMODE == 1) {
                float v1[8];
                load8f(in1 + (size_t)node * NF, c16, v1);
#pragma unroll
                for (int j = 0; j < 8; ++j) v[j] = fast_silu(v[j] + v1[j]);
            }
#pragma unroll
            for (int j = 0; j < 8; ++j) {
                unsigned short hi = f2bf(v[j]);
                th[j] = hi;
                tl[j] = f2bf(v[j] - bf2f(hi));
            }
        } else {
#pragma unroll
            for (int j = 0; j < 8; ++j) { th[j] = 0; tl[j] = 0; }
        }
        int byte = (c16 * 16) ^ ((e & 7) << 4);
        *(uint4*)(zh + e * 256 + byte) = *(uint4*)th;
        *(uint4*)(zl + e * 256 + byte) = *(uint4*)tl;
    }
    __syncthreads();

    const int w = tid >> 6, lane = tid & 63, lr = lane & 15, lg = lane >> 4;
    const int col = w * 16 + lr;
    const float bv = (col < NF) ? b[col] : 0.f;

    f32x4 acc[4];
#pragma unroll
    for (int m = 0; m < 4; ++m) acc[m] = (f32x4){0.f, 0.f, 0.f, 0.f};

#pragma unroll
    for (int ks = 0; ks < 3; ++ks) {
        bf16x8 bh = *(const bf16x8*)(Wh + ((size_t)(ks * 6 + w) * 64 + lane) * 8);
        bf16x8 bl = *(const bf16x8*)(Wl + ((size_t)(ks * 6 + w) * 64 + lane) * 8);
#pragma unroll
        for (int m = 0; m < 4; ++m) {
            int row  = m * 16 + lr;
            int byte = (ks * 64 + lg * 16) ^ ((row & 7) << 4);
            bf16x8 ah = *(const bf16x8*)(zh + row * 256 + byte);
            bf16x8 al = *(const bf16x8*)(zl + row * 256 + byte);
            acc[m] = __builtin_amdgcn_mfma_f32_16x16x32_bf16(ah, bh, acc[m], 0, 0, 0);
            acc[m] = __builtin_amdgcn_mfma_f32_16x16x32_bf16(ah, bl, acc[m], 0, 0, 0);
            acc[m] = __builtin_amdgcn_mfma_f32_16x16x32_bf16(al, bh, acc[m], 0, 0, 0);
        }
    }

    if (POOL) {
        float psum = 0.f;
#pragma unroll
        for (int m = 0; m < 4; ++m)
#pragma unroll
            for (int r = 0; r < 4; ++r) {
                int node = n0 + m * 16 + lg * 4 + r;
                if (node < N_NODES && col < NF)
                    psum += fast_silu(acc[m][r] + bv);
            }
        psum += __shfl_down(psum, 32);
        psum += __shfl_down(psum, 16);
        if (lg == 0 && col < NF) atomicAdd(&outp[col], psum);
    } else {
#pragma unroll
        for (int m = 0; m < 4; ++m)
#pragma unroll
            for (int r = 0; r < 4; ++r) {
                int node = n0 + m * 16 + lg * 4 + r;
                if (node < N_NODES && col < NF)
                    outp[(size_t)node * NF + col] = fast_silu(acc[m][r] + bv);
            }
    }
}

// ---------------- split MLP head ----------------
__global__ __launch_bounds__(128) void mlp_a(const float* __restrict__ pooled,
                                             const float* __restrict__ glob,
                                             const float* __restrict__ W2,
                                             const float* __restrict__ b2,
                                             float* __restrict__ g1)
{
    __shared__ float vin[NF + GF];
    const int t = threadIdx.x;
    for (int i = t; i < NF + GF; i += 128)
        vin[i] = (i < NF) ? pooled[i] * (1.0f / (float)N_NODES) : glob[i - NF];
    __syncthreads();
    const int col = blockIdx.x * 128 + t;
    float a = b2[col];
    for (int k = 0; k < NF + GF; ++k) a = fmaf(vin[k], W2[k * 1024 + col], a);
    g1[col] = fast_silu(a);
}

__global__ __launch_bounds__(128) void mlp_b(const float* __restrict__ g1,
                                             const float* __restrict__ W3,
                                             const float* __restrict__ b3,
                                             float* __restrict__ g2)
{
    __shared__ float vin[1024];
    const int t = threadIdx.x;
    for (int i = t; i < 1024; i += 128) vin[i] = g1[i];
    __syncthreads();
    const int col = blockIdx.x * 128 + t;
    float a = b3[col];
    for (int k = 0; k < 1024; ++k) a = fmaf(vin[k], W3[k * 512 + col], a);
    g2[col] = fast_silu(a);
}

__global__ __launch_bounds__(512) void mlp_c(const float* __restrict__ g2,
    const float* __restrict__ W4, const float* __restrict__ b4,
    const float* __restrict__ W5, const float* __restrict__ b5,
    const float* __restrict__ W6, const float* __restrict__ b6,
    const float* __restrict__ W7, const float* __restrict__ b7,
    float* __restrict__ out)
{
    __shared__ float va[512], vb[256];
    const int t = threadIdx.x;
    va[t] = g2[t];
    __syncthreads();

    if (t < 256) { // fc4: 512 -> 256
        float a = b4[t];
        for (int k = 0; k < 512; ++k) a = fmaf(va[k], W4[k * 256 + t], a);
        vb[t] = fast_silu(a);
    }
    __syncthreads();
    if (t < 128) { // fc5: 256 -> 128
        float a = b5[t];
        for (int k = 0; k < 256; ++k) a = fmaf(vb[k], W5[k * 128 + t], a);
        va[t] = fast_silu(a);
    }
    __syncthreads();
    if (t < 64) { // fc6: 128 -> 64
        float a = b6[t];
        for (int k = 0; k < 128; ++k) a = fmaf(va[k], W6[k * 64 + t], a);
        vb[t] = fast_silu(a);
    }
    __syncthreads();
    if (t < 64) { // fc7: 64 -> 1
        float p = vb[t] * W7[t];
        for (int off = 32; off; off >>= 1) p += __shfl_down(p, off);
        if (t == 0) out[0] = p + b7[0];
    }
}

// ---------------- launch ----------------
extern "C" void kernel_launch(void* const* d_in, const int* in_sizes, int n_in,
                              void* d_out, int out_size, void* d_ws, size_t ws_size,
                              hipStream_t stream)
{
    (void)in_sizes; (void)n_in; (void)out_size;

    const float* x    = (const float*)d_in[0];
    const int*   ei   = (const int*)d_in[1];
    const float* ea   = (const float*)d_in[2];
    const float* glob = (const float*)d_in[3];
    const float* cWf[3] = {(const float*)d_in[5],  (const float*)d_in[9],  (const float*)d_in[13]};
    const float* cbf[3] = {(const float*)d_in[6],  (const float*)d_in[10], (const float*)d_in[14]};
    const float* cWs[3] = {(const float*)d_in[7],  (const float*)d_in[11], (const float*)d_in[15]};
    const float* cbs[3] = {(const float*)d_in[8],  (const float*)d_in[12], (const float*)d_in[16]};
    const float* fc1W = (const float*)d_in[17]; const float* fc1b = (const float*)d_in[18];
    const float* W2 = (const float*)d_in[19];   const float* b2 = (const float*)d_in[20];
    const float* W3 = (const float*)d_in[21];   const float* b3 = (const float*)d_in[22];
    const float* W4 = (const float*)d_in[23];   const float* b4 = (const float*)d_in[24];
    const float* W5 = (const float*)d_in[25];   const float* b5 = (const float*)d_in[26];
    const float* W6 = (const float*)d_in[27];   const float* b6 = (const float*)d_in[28];
    const float* W7 = (const float*)d_in[29];   const float* b7 = (const float*)d_in[30];
    float* out = (float*)d_out;

    const size_t H = (size_t)N_NODES * NF;
    float* h1   = (float*)d_ws;                              // fp32 node state
    float* h2   = h1 + H;
    float* aggA = h2 + H;
    float* aggB = aggA + H;
    float* pooled = aggB + H;                                // 128
    float* g1 = pooled + 128;                                // 1024
    float* g2 = g1 + 1024;                                   // 512
    unsigned short* WcNh = (unsigned short*)(g2 + 512);      // 3*36864 bf16
    unsigned short* WcNl = WcNh + 3 * (size_t)36864;
    unsigned short* WcFh = WcNl + 3 * (size_t)36864;         // 9216 bf16
    unsigned short* WcFl = WcFh + (size_t)WCF_ELEMS;
    _Float16* WcEh = (_Float16*)(WcFl + (size_t)WCF_ELEMS);  // 3*12288 f16
    _Float16* WcEl = WcEh + 3 * (size_t)12288;
    float2* D2 = (float2*)(WcEl + 3 * (size_t)12288);        // N*96 float2
    _Float16* Sh = (_Float16*)(D2 + (size_t)N_NODES * 96);   // N*96 f16x2
    int* bins   = (int*)(Sh + (size_t)2 * N_NODES * 96);
    int* cursor = bins + N_NODES;
    int* perm   = cursor + N_NODES;
    int* invp   = perm + N_EDGES;
    int* s_src  = invp + N_EDGES;
    int* s_dst  = s_src + N_EDGES;
    _Float16* ebf = (_Float16*)(s_dst + N_EDGES);            // E*48 f16 (sorted)
    const size_t need_full = (size_t)((char*)(ebf + (size_t)N_EDGES * NEP) - (char*)d_ws);
    const bool use_eb = ws_size >= need_full;

    const int nEdgeBlocks = N_EDGES / 64;                    // 12500
    const int nNodeBlocks = (N_NODES + 63) / 64;             // 782

    // one-time: sort edges by dst, scatter ea to sorted f16, convert weights
    hipMemsetAsync(bins, 0, N_NODES * sizeof(int), stream);
    hist_kernel<<<(N_EDGES + 255) / 256, 256, 0, stream>>>(ei, bins);
    scan_kernel<<<1, 1024, 0, stream>>>(bins, cursor);
    place_kernel<<<(N_EDGES + 255) / 256, 256, 0, stream>>>(ei, cursor, perm, invp, s_src, s_dst);
    if (use_eb)
        permute_ea16s<<<(int)(((long)N_EDGES * NEP + 255) / 256), 256, 0, stream>>>(ea, invp, ebf);
    convert_all<<<612, 256, 0, stream>>>(cWf[0], cWs[0], cWf[1], cWs[1], cWf[2], cWs[2],
                                         fc1W, WcNh, WcNl, WcEh, WcEl, WcFh, WcFl);

    // conv layers (fused: silu+residual+stage+agg-zero inside node_mfma_f)
    node_mfma_f<0><<<nNodeBlocks, 384, 0, stream>>>(x, nullptr, nullptr,
        WcNh, WcNl, cbf[0], cbs[0], D2, Sh, aggA);
    if (use_eb)
        edge_mfma10<true><<<nEdgeBlocks, 384, 0, stream>>>(s_src, s_dst, perm, ea, ebf,
            WcEh, WcEl, D2, Sh, aggA, nEdgeBlocks);
    else
        edge_mfma10<false><<<nEdgeBlocks, 384, 0, stream>>>(s_src, s_dst, perm, ea, ebf,
            WcEh, WcEl, D2, Sh, aggA, nEdgeBlocks);

    node_mfma_f<1><<<nNodeBlocks, 384, 0, stream>>>(x, aggA, h1,
        WcNh + (size_t)36864, WcNl + (size_t)36864, cbf[1], cbs[1], D2, Sh, aggB);
    if (use_eb)
        edge_mfma10<true><<<nEdgeBlocks, 384, 0, stream>>>(s_src, s_dst, perm, ea, ebf,
            WcEh + (size_t)12288, WcEl + (size_t)12288, D2, Sh, aggB, nEdgeBlocks);
    else
        edge_mfma10<false><<<nEdgeBlocks, 384, 0, stream>>>(s_src, s_dst, perm, ea, ebf,
            WcEh + (size_t)12288, WcEl + (size_t)12288, D2, Sh, aggB, nEdgeBlocks);

    node_mfma_f<1><<<nNodeBlocks, 384, 0, stream>>>(h1, aggB, h2,
        WcNh + (size_t)2 * 36864, WcNl + (size_t)2 * 36864, cbf[2], cbs[2], D2, Sh, aggA);
    if (use_eb)
        edge_mfma10<true><<<nEdgeBlocks, 384, 0, stream>>>(s_src, s_dst, perm, ea, ebf,
            WcEh + (size_t)2 * 12288, WcEl + (size_t)2 * 12288, D2, Sh, aggA, nEdgeBlocks);
    else
        edge_mfma10<false><<<nEdgeBlocks, 384, 0, stream>>>(s_src, s_dst, perm, ea, ebf,
            WcEh + (size_t)2 * 12288, WcEl + (size_t)2 * 12288, D2, Sh, aggA, nEdgeBlocks);

    // fc1 #1: stage silu(h2 + aggA), write fp32 -> aggB
    fc_mfma_f<1, false><<<nNodeBlocks, 384, 0, stream>>>(h2, aggA, WcFh, WcFl, fc1b, aggB);
    // fc1 #2: stage aggB, fused mean-pool into pooled
    hipMemsetAsync(pooled, 0, NF * sizeof(float), stream);
    fc_mfma_f<0, true><<<nNodeBlocks, 384, 0, stream>>>(aggB, nullptr, WcFh, WcFl, fc1b, pooled);

    // MLP head (split)
    mlp_a<<<8, 128, 0, stream>>>(pooled, glob, W2, b2, g1);
    mlp_b<<<4, 128, 0, stream>>>(g1, W3, b3, g2);
    mlp_c<<<1, 512, 0, stream>>>(g2, W4, b4, W5, b5, W6, b6, W7, b7, out);
}

// Round 14
// 1259.683 us; speedup vs baseline: 1.0741x; 1.0188x over previous
//
#include <hip/hip_runtime.h>
#include <math.h>

// ---------------- problem constants ----------------
#define N_NODES 50000
#define N_EDGES 800000
#define NF 92           // node features
#define EF 41           // edge features
#define GF 180          // global attr
#define NEP 48          // padded f16 edge_attr row (dst-sorted)
#define EBE 32          // edges per block in edge kernel

#define WCN_ELEMS (3 * 24 * 64 * 8)   // node-GEMM weights per layer (bf16 hi/lo)
#define WCE_ELEMS (2 * 12 * 64 * 8)   // edge-GEMM weights per layer (f16 hi/lo)
#define WCF_ELEMS (3 * 6 * 64 * 8)    // fc1 weights (bf16 hi/lo)

typedef __attribute__((ext_vector_type(8))) short bf16x8;
typedef __attribute__((ext_vector_type(8))) _Float16 f16x8;
typedef __attribute__((ext_vector_type(2))) _Float16 f16x2;
typedef __attribute__((ext_vector_type(4))) float f32x4;

#define L2E 1.44269504f
#define LN2 0.69314718f

__device__ __forceinline__ float fast_sigmoid(float x) {
    return __builtin_amdgcn_rcpf(1.0f + __builtin_amdgcn_exp2f(-x * L2E));
}
__device__ __forceinline__ float fast_softplus(float x) {
    float t = __builtin_amdgcn_exp2f(-fabsf(x) * L2E);
    return fmaxf(x, 0.0f) + __builtin_amdgcn_logf(1.0f + t) * LN2;
}
__device__ __forceinline__ float fast_silu(float x) { return x * fast_sigmoid(x); }

__device__ __forceinline__ unsigned short f2bf(float x) {
    union { float f; unsigned u; } v; v.f = x;
    unsigned r = v.u + 0x7FFF + ((v.u >> 16) & 1);   // RNE
    return (unsigned short)(r >> 16);
}
__device__ __forceinline__ float bf2f(unsigned short h) {
    union { unsigned u; float f; } v; v.u = ((unsigned)h) << 16; return v.f;
}

// bijective XCD-aware block swizzle (m204 variant)
__device__ __forceinline__ int xcd_swz(int bid, int nwg) {
    int q = nwg >> 3, r = nwg & 7;
    int xcd = bid & 7, idx = bid >> 3;
    return (xcd < r ? xcd * (q + 1) : r * (q + 1) + (xcd - r) * q) + idx;
}

// load 8 fp32 from a 92-float row at cols [c16*8, c16*8+8), zero-padded past 91
__device__ __forceinline__ void load8f(const float* __restrict__ rowp, int c16, float v[8]) {
    if (c16 < 11) {
        float4 a = *(const float4*)(rowp + c16 * 8);
        float4 b = *(const float4*)(rowp + c16 * 8 + 4);
        v[0]=a.x; v[1]=a.y; v[2]=a.z; v[3]=a.w; v[4]=b.x; v[5]=b.y; v[6]=b.z; v[7]=b.w;
    } else {
        float4 a = *(const float4*)(rowp + 88);
        v[0]=a.x; v[1]=a.y; v[2]=a.z; v[3]=a.w; v[4]=0.f; v[5]=0.f; v[6]=0.f; v[7]=0.f;
    }
}

// ---------------- sort infra: counting sort of edges by dst ----------------
__global__ __launch_bounds__(256) void hist_kernel(const int* __restrict__ ei,
                                                   int* __restrict__ bins)
{
    int e = blockIdx.x * 256 + threadIdx.x;
    if (e < N_EDGES) atomicAdd(&bins[ei[N_EDGES + e]], 1);
}

__global__ __launch_bounds__(1024) void scan_kernel(const int* __restrict__ bins,
                                                    int* __restrict__ cursor)
{
    __shared__ int tot[1024];
    const int t = threadIdx.x;
    const int C = (N_NODES + 1023) / 1024;
    const int i0 = t * C, i1 = min(i0 + C, N_NODES);
    int s = 0;
    for (int i = i0; i < i1; ++i) s += bins[i];
    tot[t] = s;
    __syncthreads();
    for (int off = 1; off < 1024; off <<= 1) {
        int v = (t >= off) ? tot[t - off] : 0;
        __syncthreads();
        tot[t] += v;
        __syncthreads();
    }
    int run = tot[t] - s;   // exclusive base
    for (int i = i0; i < i1; ++i) { cursor[i] = run; run += bins[i]; }
}

__global__ __launch_bounds__(256) void place_kernel(const int* __restrict__ ei,
                                                    int* __restrict__ cursor,
                                                    int* __restrict__ perm,
                                                    int* __restrict__ invp,
                                                    int* __restrict__ s_src,
                                                    int* __restrict__ s_dst)
{
    int e = blockIdx.x * 256 + threadIdx.x;
    if (e < N_EDGES) {
        int d = ei[N_EDGES + e];
        int pos = atomicAdd(&cursor[d], 1);
        perm[pos] = e;
        invp[e] = pos;
        s_dst[pos] = d;
        s_src[pos] = ei[e];
    }
}

// ---------------- one-time: scatter ea into dst-sorted f16 rows (coalesced read) ----------------
__global__ __launch_bounds__(256) void permute_ea16s(const float* __restrict__ ea,
                                                     const int* __restrict__ invp,
                                                     _Float16* __restrict__ ebf)
{
    long i = (long)blockIdx.x * 256 + threadIdx.x;
    if (i >= (long)N_EDGES * NEP) return;
    long e = i / NEP; int c = (int)(i - e * NEP);
    float v = (c < EF) ? ea[e * EF + c] : 0.0f;
    ebf[(size_t)invp[e] * NEP + c] = (_Float16)v;
}

// ---------------- merged weight conversion (all layers, node+edge+fc) ----------------
__global__ __launch_bounds__(256) void convert_all(
    const float* __restrict__ Wf0, const float* __restrict__ Ws0,
    const float* __restrict__ Wf1, const float* __restrict__ Ws1,
    const float* __restrict__ Wf2, const float* __restrict__ Ws2,
    const float* __restrict__ fc1W,
    unsigned short* __restrict__ WcNh, unsigned short* __restrict__ WcNl,
    _Float16* __restrict__ WcEh, _Float16* __restrict__ WcEl,
    unsigned short* __restrict__ WcFh, unsigned short* __restrict__ WcFl)
{
    const int bid = blockIdx.x;
    if (bid < 432) {
        int l = bid / 144;
        int idx = (bid - l * 144) * 256 + threadIdx.x;
        if (idx >= 36864) return;
        const float* Wf = (l == 0) ? Wf0 : (l == 1) ? Wf1 : Wf2;
        const float* Ws = (l == 0) ? Ws0 : (l == 1) ? Ws1 : Ws2;
        int j    = idx & 7;
        int lane = (idx >> 3) & 63;
        int nt   = (idx >> 9) % 24;
        int ks   = idx / (24 * 512);
        int k = ks * 32 + ((lane >> 4) * 8) + j;
        int n = nt * 16 + (lane & 15);
        int t = n / 96, col = n % 96;
        float val = 0.f;
        if (k < 92 && col < 92) {
            const float* W = (t < 2) ? Wf : Ws;
            int rowoff = (t & 1) ? 92 : 0;
            val = W[(rowoff + k) * NF + col];
        }
        unsigned short hi = f2bf(val);
        size_t o = (size_t)l * 36864 + idx;
        WcNh[o] = hi;
        WcNl[o] = f2bf(val - bf2f(hi));
    } else if (bid < 576) {
        int b2 = bid - 432;
        int l = b2 / 48;
        int idx = (b2 - l * 48) * 256 + threadIdx.x;
        if (idx >= 12288) return;
        const float* Wf = (l == 0) ? Wf0 : (l == 1) ? Wf1 : Wf2;
        const float* Ws = (l == 0) ? Ws0 : (l == 1) ? Ws1 : Ws2;
        int j    = idx & 7;
        int lane = (idx >> 3) & 63;
        int nt   = (idx >> 9) % 12;
        int ks   = idx / (12 * 512);
        int k = ks * 32 + ((lane >> 4) * 8) + j;
        int n = nt * 16 + (lane & 15);
        float val = 0.f;
        if (k < EF) {
            if (n < 92)                  val = Wf[(184 + k) * NF + n];
            else if (n >= 96 && n < 188) val = Ws[(184 + k) * NF + (n - 96)];
        }
        _Float16 hi = (_Float16)val;
        size_t o = (size_t)l * 12288 + idx;
        WcEh[o] = hi;
        WcEl[o] = (_Float16)(val - (float)hi);
    } else {
        int idx = (bid - 576) * 256 + threadIdx.x;
        if (idx >= WCF_ELEMS) return;
        int j    = idx & 7;
        int lane = (idx >> 3) & 63;
        int nt   = (idx >> 9) % 6;
        int ks   = idx / (6 * 512);
        int k = ks * 32 + ((lane >> 4) * 8) + j;
        int n = nt * 16 + (lane & 15);
        float val = (k < 92 && n < 92) ? fc1W[k * NF + n] : 0.f;
        unsigned short hi = f2bf(val);
        WcFh[idx] = hi;
        WcFl[idx] = f2bf(val - bf2f(hi));
    }
}

// ---------------- fused node GEMM ----------------
template <int SMODE>
__global__ __launch_bounds__(384) void node_mfma_f(
    const float* __restrict__ in0, const float* __restrict__ in1,
    float* __restrict__ h_out,
    const unsigned short* __restrict__ Wh, const unsigned short* __restrict__ Wl,
    const float* __restrict__ bf, const float* __restrict__ bs,
    float2* __restrict__ D2, _Float16* __restrict__ Sh,
    float* __restrict__ agg_zero)
{
    __shared__ char zz[2 * 64 * 256];     // hi | lo, 256B rows
    const int tid = threadIdx.x;
    const int n0 = blockIdx.x * 64;
    char* const zh = zz;
    char* const zl = zz + 64 * 256;

    for (int u = tid; u < 64 * 23; u += 384) {
        int e = u / 23, q = u - e * 23;
        int node = n0 + e;
        if (node < N_NODES)
            ((float4*)(agg_zero + (size_t)node * NF))[q] = make_float4(0.f, 0.f, 0.f, 0.f);
    }

    for (int u = tid; u < 64 * 16; u += 384) {
        int e = u >> 4, c16 = u & 15;
        int node = n0 + e;
        unsigned short th[8], tl[8];
        if (c16 < 12 && node < N_NODES) {
            float v[8];
            load8f(in0 + (size_t)node * NF, c16, v);
            if (SMODE == 1) {
                float v1[8];
                load8f(in1 + (size_t)node * NF, c16, v1);
#pragma unroll
                for (int j = 0; j < 8; ++j) v[j] = fast_silu(v[j] + v1[j]);
                float* hr = h_out + (size_t)node * NF;
                if (c16 < 11) {
                    *(float4*)(hr + c16 * 8)     = make_float4(v[0], v[1], v[2], v[3]);
                    *(float4*)(hr + c16 * 8 + 4) = make_float4(v[4], v[5], v[6], v[7]);
                } else {
                    *(float4*)(hr + 88) = make_float4(v[0], v[1], v[2], v[3]);
                }
            }
#pragma unroll
            for (int j = 0; j < 8; ++j) {
                unsigned short hi = f2bf(v[j]);
                th[j] = hi;
                tl[j] = f2bf(v[j] - bf2f(hi));
            }
        } else {
#pragma unroll
            for (int j = 0; j < 8; ++j) { th[j] = 0; tl[j] = 0; }
        }
        int byte = (c16 * 16) ^ ((e & 7) << 4);
        *(uint4*)(zh + e * 256 + byte) = *(uint4*)th;
        *(uint4*)(zl + e * 256 + byte) = *(uint4*)tl;
    }
    __syncthreads();

    const int w = tid >> 6, lane = tid & 63, lr = lane & 15, lg = lane >> 4;
    const int col = w * 16 + lr;
    const float bfv = (col < NF) ? bf[col] : 0.f;
    const float bsv = (col < NF) ? bs[col] : 0.f;

    float keepD[4][4], keepS[4][4];

    for (int ntx = 0; ntx < 4; ++ntx) {
        const int nt = w + 6 * ntx;      // table t == ntx, col fixed
        f32x4 acc[4];
#pragma unroll
        for (int m = 0; m < 4; ++m) acc[m] = (f32x4){0.f, 0.f, 0.f, 0.f};

#pragma unroll
        for (int ks = 0; ks < 3; ++ks) {
            bf16x8 bh = *(const bf16x8*)(Wh + ((size_t)(ks * 24 + nt) * 64 + lane) * 8);
            bf16x8 bl = *(const bf16x8*)(Wl + ((size_t)(ks * 24 + nt) * 64 + lane) * 8);
#pragma unroll
            for (int m = 0; m < 4; ++m) {
                int row  = m * 16 + lr;
                int byte = (ks * 64 + lg * 16) ^ ((row & 7) << 4);
                bf16x8 ah = *(const bf16x8*)(zh + row * 256 + byte);
                bf16x8 al = *(const bf16x8*)(zl + row * 256 + byte);
                acc[m] = __builtin_amdgcn_mfma_f32_16x16x32_bf16(ah, bh, acc[m], 0, 0, 0);
                acc[m] = __builtin_amdgcn_mfma_f32_16x16x32_bf16(ah, bl, acc[m], 0, 0, 0);
                acc[m] = __builtin_amdgcn_mfma_f32_16x16x32_bf16(al, bh, acc[m], 0, 0, 0);
            }
        }

        if (col < NF) {
#pragma unroll
            for (int m = 0; m < 4; ++m) {
#pragma unroll
                for (int r = 0; r < 4; ++r) {
                    int node = n0 + m * 16 + lg * 4 + r;
                    if (ntx == 0) keepD[m][r] = acc[m][r] + bfv;        // Pf+bf
                    else if (ntx == 1) keepS[m][r] = acc[m][r];         // Qf
                    else if (ntx == 2) {                                // Ps+bs -> write D
                        if (node < N_NODES)
                            D2[(size_t)node * 96 + col] =
                                make_float2(keepD[m][r], acc[m][r] + bsv);
                    } else {                                            // Qs -> write S
                        if (node < N_NODES) {
                            f16x2 hv;
                            hv[0] = (_Float16)keepS[m][r];
                            hv[1] = (_Float16)acc[m][r];
                            *(f16x2*)(Sh + ((size_t)node * 96 + col) * 2) = hv;
                        }
                    }
                }
            }
        }
    }
}

// ---------------- edge kernel: 32 edges/block (halved M for occupancy) ----------------
template <bool EB>
__global__ __launch_bounds__(384) void edge_mfma12(
    const int* __restrict__ s_src, const int* __restrict__ s_dst,
    const int* __restrict__ perm, const float* __restrict__ ea,
    const _Float16* __restrict__ ebf,
    const _Float16* __restrict__ Wh, const _Float16* __restrict__ Wl,
    const float2* __restrict__ D2, const _Float16* __restrict__ Sh,
    float* __restrict__ agg, int nblk)
{
    __shared__ char zb[EBE * 128];    // z: 32 edges x 64 f16 (128B rows), swizzled
    __shared__ int sdst[EBE], ssrc[EBE], sperm[EBE];

    const int tid = threadIdx.x;
    const int bid = xcd_swz(blockIdx.x, nblk);
    const size_t e0 = (size_t)bid * EBE;

    if (tid < EBE) {
        ssrc[tid] = s_src[e0 + tid];
        sdst[tid] = s_dst[e0 + tid];
        if (!EB) sperm[tid] = perm[e0 + tid];
    }
    if (!EB) __syncthreads();

    if (tid < EBE * 8) {
        int e = tid >> 3, c16 = tid & 7;
        uint4 v = make_uint4(0u, 0u, 0u, 0u);
        if (EB) {
            if (c16 < 6) v = *(const uint4*)(ebf + (e0 + e) * NEP + c16 * 8);
        } else {
            if (c16 < 6) {
                const float* ear = ea + (size_t)sperm[e] * EF;
                _Float16 t[8];
#pragma unroll
                for (int jj = 0; jj < 8; ++jj) {
                    int cc = c16 * 8 + jj;
                    t[jj] = (_Float16)((cc < EF) ? ear[cc] : 0.0f);
                }
                v = *(uint4*)t;
            }
        }
        int byte = (c16 * 16) ^ ((e & 7) << 4);
        *(uint4*)(zb + e * 128 + byte) = v;
    }
    __syncthreads();

    const int w = tid >> 6, lane = tid & 63, lr = lane & 15, lg = lane >> 4;
    const int c = w * 16 + lr;

    // prefetch BEFORE MFMA: 8 random S half2 + 2 run-start D float2
    f16x2 sv[2][4];
    float2 dv0[2];
#pragma unroll
    for (int m = 0; m < 2; ++m) {
#pragma unroll
        for (int r = 0; r < 4; ++r)
            sv[m][r] = *(const f16x2*)(Sh + ((size_t)ssrc[m * 16 + lg * 4 + r] * 96 + c) * 2);
        dv0[m] = D2[(size_t)sdst[m * 16 + lg * 4] * 96 + c];
    }

    f32x4 accF[2], accS[2];
#pragma unroll
    for (int m = 0; m < 2; ++m) {
        accF[m] = (f32x4){0.f, 0.f, 0.f, 0.f};
        accS[m] = (f32x4){0.f, 0.f, 0.f, 0.f};
    }

#pragma unroll
    for (int ks = 0; ks < 2; ++ks) {
        f16x8 bFh = *(const f16x8*)(Wh + ((size_t)(ks * 12 + w)     * 64 + lane) * 8);
        f16x8 bFl = *(const f16x8*)(Wl + ((size_t)(ks * 12 + w)     * 64 + lane) * 8);
        f16x8 bSh = *(const f16x8*)(Wh + ((size_t)(ks * 12 + w + 6) * 64 + lane) * 8);
        f16x8 bSl = *(const f16x8*)(Wl + ((size_t)(ks * 12 + w + 6) * 64 + lane) * 8);
#pragma unroll
        for (int m = 0; m < 2; ++m) {
            int row  = m * 16 + lr;
            int byte = (ks * 64 + lg * 16) ^ ((row & 7) << 4);
            f16x8 a = *(const f16x8*)(zb + row * 128 + byte);
            accF[m] = __builtin_amdgcn_mfma_f32_16x16x32_f16(a, bFh, accF[m], 0, 0, 0);
            accF[m] = __builtin_amdgcn_mfma_f32_16x16x32_f16(a, bFl, accF[m], 0, 0, 0);
            accS[m] = __builtin_amdgcn_mfma_f32_16x16x32_f16(a, bSh, accS[m], 0, 0, 0);
            accS[m] = __builtin_amdgcn_mfma_f32_16x16x32_f16(a, bSl, accS[m], 0, 0, 0);
        }
    }

    if (c < NF) {
#pragma unroll
        for (int m = 0; m < 2; ++m) {
            const int eb0 = m * 16 + lg * 4;
            int prev = sdst[eb0];
            float2 dv = dv0[m];
            float accum = 0.f;
#pragma unroll
            for (int r = 0; r < 4; ++r) {
                int dst = sdst[eb0 + r];
                if (dst != prev) {
                    atomicAdd(&agg[(size_t)prev * NF + c], accum);
                    accum = 0.f;
                    prev = dst;
                    dv = D2[(size_t)dst * 96 + c];
                }
                float f = accF[m][r] + dv.x + (float)sv[m][r][0];
                float s = accS[m][r] + dv.y + (float)sv[m][r][1];
                accum += fast_sigmoid(f) * fast_softplus(s);
            }
            atomicAdd(&agg[(size_t)prev * NF + c], accum);
        }
    }
}

// ---------------- fused fc1 via split-bf16 MFMA ----------------
template <int SMODE, bool POOL>
__global__ __launch_bounds__(384) void fc_mfma_f(
    const float* __restrict__ in0, const float* __restrict__ in1,
    const unsigned short* __restrict__ Wh, const unsigned short* __restrict__ Wl,
    const float* __restrict__ b, float* __restrict__ outp)
{
    __shared__ char zz[2 * 64 * 256];
    const int tid = threadIdx.x;
    const int n0 = blockIdx.x * 64;
    char* const zh = zz;
    char* const zl = zz + 64 * 256;

    for (int u = tid; u < 64 * 16; u += 384) {
        int e = u >> 4, c16 = u & 15;
        int node = n0 + e;
        unsigned short th[8], tl[8];
        if (c16 < 12 && node < N_NODES) {
            float v[8];
            load8f(in0 + (size_t)node * NF, c16, v);
            if (SMODE == 1) {
                float v1[8];
                load8f(in1 + (size_t)node * NF, c16, v1);
#pragma unroll
                for (int j = 0; j < 8; ++j) v[j] = fast_silu(v[j] + v1[j]);
            }
#pragma unroll
            for (int j = 0; j < 8; ++j) {
                unsigned short hi = f2bf(v[j]);
                th[j] = hi;
                tl[j] = f2bf(v[j] - bf2f(hi));
            }
        } else {
#pragma unroll
            for (int j = 0; j < 8; ++j) { th[j] = 0; tl[j] = 0; }
        }
        int byte = (c16 * 16) ^ ((e & 7) << 4);
        *(uint4*)(zh + e * 256 + byte) = *(uint4*)th;
        *(uint4*)(zl + e * 256 + byte) = *(uint4*)tl;
    }
    __syncthreads();

    const int w = tid >> 6, lane = tid & 63, lr = lane & 15, lg = lane >> 4;
    const int col = w * 16 + lr;
    const float bv = (col < NF) ? b[col] : 0.f;

    f32x4 acc[4];
#pragma unroll
    for (int m = 0; m < 4; ++m) acc[m] = (f32x4){0.f, 0.f, 0.f, 0.f};

#pragma unroll
    for (int ks = 0; ks < 3; ++ks) {
        bf16x8 bh = *(const bf16x8*)(Wh + ((size_t)(ks * 6 + w) * 64 + lane) * 8);
        bf16x8 bl = *(const bf16x8*)(Wl + ((size_t)(ks * 6 + w) * 64 + lane) * 8);
#pragma unroll
        for (int m = 0; m < 4; ++m) {
            int row  = m * 16 + lr;
            int byte = (ks * 64 + lg * 16) ^ ((row & 7) << 4);
            bf16x8 ah = *(const bf16x8*)(zh + row * 256 + byte);
            bf16x8 al = *(const bf16x8*)(zl + row * 256 + byte);
            acc[m] = __builtin_amdgcn_mfma_f32_16x16x32_bf16(ah, bh, acc[m], 0, 0, 0);
            acc[m] = __builtin_amdgcn_mfma_f32_16x16x32_bf16(ah, bl, acc[m], 0, 0, 0);
            acc[m] = __builtin_amdgcn_mfma_f32_16x16x32_bf16(al, bh, acc[m], 0, 0, 0);
        }
    }

    if (POOL) {
        float psum = 0.f;
#pragma unroll
        for (int m = 0; m < 4; ++m)
#pragma unroll
            for (int r = 0; r < 4; ++r) {
                int node = n0 + m * 16 + lg * 4 + r;
                if (node < N_NODES && col < NF)
                    psum += fast_silu(acc[m][r] + bv);
            }
        psum += __shfl_down(psum, 32);
        psum += __shfl_down(psum, 16);
        if (lg == 0 && col < NF) atomicAdd(&outp[col], psum);
    } else {
#pragma unroll
        for (int m = 0; m < 4; ++m)
#pragma unroll
            for (int r = 0; r < 4; ++r) {
                int node = n0 + m * 16 + lg * 4 + r;
                if (node < N_NODES && col < NF)
                    outp[(size_t)node * NF + col] = fast_silu(acc[m][r] + bv);
            }
    }
}

// ---------------- split MLP head ----------------
__global__ __launch_bounds__(128) void mlp_a(const float* __restrict__ pooled,
                                             const float* __restrict__ glob,
                                             const float* __restrict__ W2,
                                             const float* __restrict__ b2,
                                             float* __restrict__ g1)
{
    __shared__ float vin[NF + GF];
    const int t = threadIdx.x;
    for (int i = t; i < NF + GF; i += 128)
        vin[i] = (i < NF) ? pooled[i] * (1.0f / (float)N_NODES) : glob[i - NF];
    __syncthreads();
    const int col = blockIdx.x * 128 + t;
    float a = b2[col];
    for (int k = 0; k < NF + GF; ++k) a = fmaf(vin[k], W2[k * 1024 + col], a);
    g1[col] = fast_silu(a);
}

__global__ __launch_bounds__(128) void mlp_b(const float* __restrict__ g1,
                                             const float* __restrict__ W3,
                                             const float* __restrict__ b3,
                                             float* __restrict__ g2)
{
    __shared__ float vin[1024];
    const int t = threadIdx.x;
    for (int i = t; i < 1024; i += 128) vin[i] = g1[i];
    __syncthreads();
    const int col = blockIdx.x * 128 + t;
    float a = b3[col];
    for (int k = 0; k < 1024; ++k) a = fmaf(vin[k], W3[k * 512 + col], a);
    g2[col] = fast_silu(a);
}

__global__ __launch_bounds__(512) void mlp_c(const float* __restrict__ g2,
    const float* __restrict__ W4, const float* __restrict__ b4,
    const float* __restrict__ W5, const float* __restrict__ b5,
    const float* __restrict__ W6, const float* __restrict__ b6,
    const float* __restrict__ W7, const float* __restrict__ b7,
    float* __restrict__ out)
{
    __shared__ float va[512], vb[256];
    const int t = threadIdx.x;
    va[t] = g2[t];
    __syncthreads();

    if (t < 256) { // fc4: 512 -> 256
        float a = b4[t];
        for (int k = 0; k < 512; ++k) a = fmaf(va[k], W4[k * 256 + t], a);
        vb[t] = fast_silu(a);
    }
    __syncthreads();
    if (t < 128) { // fc5: 256 -> 128
        float a = b5[t];
        for (int k = 0; k < 256; ++k) a = fmaf(vb[k], W5[k * 128 + t], a);
        va[t] = fast_silu(a);
    }
    __syncthreads();
    if (t < 64) { // fc6: 128 -> 64
        float a = b6[t];
        for (int k = 0; k < 128; ++k) a = fmaf(va[k], W6[k * 64 + t], a);
        vb[t] = fast_silu(a);
    }
    __syncthreads();
    if (t < 64) { // fc7: 64 -> 1
        float p = vb[t] * W7[t];
        for (int off = 32; off; off >>= 1) p += __shfl_down(p, off);
        if (t == 0) out[0] = p + b7[0];
    }
}

// ---------------- launch ----------------
extern "C" void kernel_launch(void* const* d_in, const int* in_sizes, int n_in,
                              void* d_out, int out_size, void* d_ws, size_t ws_size,
                              hipStream_t stream)
{
    (void)in_sizes; (void)n_in; (void)out_size;

    const float* x    = (const float*)d_in[0];
    const int*   ei   = (const int*)d_in[1];
    const float* ea   = (const float*)d_in[2];
    const float* glob = (const float*)d_in[3];
    const float* cWf[3] = {(const float*)d_in[5],  (const float*)d_in[9],  (const float*)d_in[13]};
    const float* cbf[3] = {(const float*)d_in[6],  (const float*)d_in[10], (const float*)d_in[14]};
    const float* cWs[3] = {(const float*)d_in[7],  (const float*)d_in[11], (const float*)d_in[15]};
    const float* cbs[3] = {(const float*)d_in[8],  (const float*)d_in[12], (const float*)d_in[16]};
    const float* fc1W = (const float*)d_in[17]; const float* fc1b = (const float*)d_in[18];
    const float* W2 = (const float*)d_in[19];   const float* b2 = (const float*)d_in[20];
    const float* W3 = (const float*)d_in[21];   const float* b3 = (const float*)d_in[22];
    const float* W4 = (const float*)d_in[23];   const float* b4 = (const float*)d_in[24];
    const float* W5 = (const float*)d_in[25];   const float* b5 = (const float*)d_in[26];
    const float* W6 = (const float*)d_in[27];   const float* b6 = (const float*)d_in[28];
    const float* W7 = (const float*)d_in[29];   const float* b7 = (const float*)d_in[30];
    float* out = (float*)d_out;

    const size_t H = (size_t)N_NODES * NF;
    float* h1   = (float*)d_ws;                              // fp32 node state
    float* h2   = h1 + H;
    float* aggA = h2 + H;
    float* aggB = aggA + H;
    float* pooled = aggB + H;                                // 128
    float* g1 = pooled + 128;                                // 1024
    float* g2 = g1 + 1024;                                   // 512
    unsigned short* WcNh = (unsigned short*)(g2 + 512);      // 3*36864 bf16
    unsigned short* WcNl = WcNh + 3 * (size_t)36864;
    unsigned short* WcFh = WcNl + 3 * (size_t)36864;         // 9216 bf16
    unsigned short* WcFl = WcFh + (size_t)WCF_ELEMS;
    _Float16* WcEh = (_Float16*)(WcFl + (size_t)WCF_ELEMS);  // 3*12288 f16
    _Float16* WcEl = WcEh + 3 * (size_t)12288;
    float2* D2 = (float2*)(WcEl + 3 * (size_t)12288);        // N*96 float2
    _Float16* Sh = (_Float16*)(D2 + (size_t)N_NODES * 96);   // N*96 f16x2
    int* bins   = (int*)(Sh + (size_t)2 * N_NODES * 96);
    int* cursor = bins + N_NODES;
    int* perm   = cursor + N_NODES;
    int* invp   = perm + N_EDGES;
    int* s_src  = invp + N_EDGES;
    int* s_dst  = s_src + N_EDGES;
    _Float16* ebf = (_Float16*)(s_dst + N_EDGES);            // E*48 f16 (sorted)
    const size_t need_full = (size_t)((char*)(ebf + (size_t)N_EDGES * NEP) - (char*)d_ws);
    const bool use_eb = ws_size >= need_full;

    const int nEdgeBlocks = N_EDGES / EBE;                   // 25000
    const int nNodeBlocks = (N_NODES + 63) / 64;             // 782

    // one-time: sort edges by dst, scatter ea to sorted f16, convert weights
    hipMemsetAsync(bins, 0, N_NODES * sizeof(int), stream);
    hist_kernel<<<(N_EDGES + 255) / 256, 256, 0, stream>>>(ei, bins);
    scan_kernel<<<1, 1024, 0, stream>>>(bins, cursor);
    place_kernel<<<(N_EDGES + 255) / 256, 256, 0, stream>>>(ei, cursor, perm, invp, s_src, s_dst);
    if (use_eb)
        permute_ea16s<<<(int)(((long)N_EDGES * NEP + 255) / 256), 256, 0, stream>>>(ea, invp, ebf);
    convert_all<<<612, 256, 0, stream>>>(cWf[0], cWs[0], cWf[1], cWs[1], cWf[2], cWs[2],
                                         fc1W, WcNh, WcNl, WcEh, WcEl, WcFh, WcFl);

    // conv layers (fused: silu+residual+stage+agg-zero inside node_mfma_f)
    node_mfma_f<0><<<nNodeBlocks, 384, 0, stream>>>(x, nullptr, nullptr,
        WcNh, WcNl, cbf[0], cbs[0], D2, Sh, aggA);
    if (use_eb)
        edge_mfma12<true><<<nEdgeBlocks, 384, 0, stream>>>(s_src, s_dst, perm, ea, ebf,
            WcEh, WcEl, D2, Sh, aggA, nEdgeBlocks);
    else
        edge_mfma12<false><<<nEdgeBlocks, 384, 0, stream>>>(s_src, s_dst, perm, ea, ebf,
            WcEh, WcEl, D2, Sh, aggA, nEdgeBlocks);

    node_mfma_f<1><<<nNodeBlocks, 384, 0, stream>>>(x, aggA, h1,
        WcNh + (size_t)36864, WcNl + (size_t)36864, cbf[1], cbs[1], D2, Sh, aggB);
    if (use_eb)
        edge_mfma12<true><<<nEdgeBlocks, 384, 0, stream>>>(s_src, s_dst, perm, ea, ebf,
            WcEh + (size_t)12288, WcEl + (size_t)12288, D2, Sh, aggB, nEdgeBlocks);
    else
        edge_mfma12<false><<<nEdgeBlocks, 384, 0, stream>>>(s_src, s_dst, perm, ea, ebf,
            WcEh + (size_t)12288, WcEl + (size_t)12288, D2, Sh, aggB, nEdgeBlocks);

    node_mfma_f<1><<<nNodeBlocks, 384, 0, stream>>>(h1, aggB, h2,
        WcNh + (size_t)2 * 36864, WcNl + (size_t)2 * 36864, cbf[2], cbs[2], D2, Sh, aggA);
    if (use_eb)
        edge_mfma12<true><<<nEdgeBlocks, 384, 0, stream>>>(s_src, s_dst, perm, ea, ebf,
            WcEh + (size_t)2 * 12288, WcEl + (size_t)2 * 12288, D2, Sh, aggA, nEdgeBlocks);
    else
        edge_mfma12<false><<<nEdgeBlocks, 384, 0, stream>>>(s_src, s_dst, perm, ea, ebf,
            WcEh + (size_t)2 * 12288, WcEl + (size_t)2 * 12288, D2, Sh, aggA, nEdgeBlocks);

    // fc1 #1: stage silu(h2 + aggA), write fp32 -> aggB
    fc_mfma_f<1, false><<<nNodeBlocks, 384, 0, stream>>>(h2, aggA, WcFh, WcFl, fc1b, aggB);
    // fc1 #2: stage aggB, fused mean-pool into pooled
    hipMemsetAsync(pooled, 0, NF * sizeof(float), stream);
    fc_mfma_f<0, true><<<nNodeBlocks, 384, 0, stream>>>(aggB, nullptr, WcFh, WcFl, fc1b, pooled);

    // MLP head (split)
    mlp_a<<<8, 128, 0, stream>>>(pooled, glob, W2, b2, g1);
    mlp_b<<<4, 128, 0, stream>>>(g1, W3, b3, g2);
    mlp_c<<<1, 512, 0, stream>>>(g2, W4, b4, W5, b5, W6, b6, W7, b7, out);
}

// Round 15
// 1231.099 us; speedup vs baseline: 1.0991x; 1.0232x over previous
//
#include <hip/hip_runtime.h>
#include <math.h>

// ---------------- problem constants ----------------
#define N_NODES 50000
#define N_EDGES 800000
#define NF 92           // node features
#define EF 41           // edge features
#define GF 180          // global attr
#define NEP 48          // padded f16 edge_attr row (dst-sorted)
#define EBE 32          // edges per block in edge kernel

#define WCF_ELEMS (3 * 6 * 64 * 8)    // fc1 weights (bf16 hi/lo)

typedef __attribute__((ext_vector_type(8))) short bf16x8;
typedef __attribute__((ext_vector_type(8))) _Float16 f16x8;
typedef __attribute__((ext_vector_type(2))) _Float16 f16x2;
typedef __attribute__((ext_vector_type(4))) float f32x4;

#define L2E 1.44269504f
#define LN2 0.69314718f

__device__ __forceinline__ float fast_sigmoid(float x) {
    return __builtin_amdgcn_rcpf(1.0f + __builtin_amdgcn_exp2f(-x * L2E));
}
__device__ __forceinline__ float fast_softplus(float x) {
    float t = __builtin_amdgcn_exp2f(-fabsf(x) * L2E);
    return fmaxf(x, 0.0f) + __builtin_amdgcn_logf(1.0f + t) * LN2;
}
__device__ __forceinline__ float fast_silu(float x) { return x * fast_sigmoid(x); }

__device__ __forceinline__ unsigned short f2bf(float x) {
    union { float f; unsigned u; } v; v.f = x;
    unsigned r = v.u + 0x7FFF + ((v.u >> 16) & 1);   // RNE
    return (unsigned short)(r >> 16);
}
__device__ __forceinline__ float bf2f(unsigned short h) {
    union { unsigned u; float f; } v; v.u = ((unsigned)h) << 16; return v.f;
}

// bijective XCD-aware block swizzle (m204 variant)
__device__ __forceinline__ int xcd_swz(int bid, int nwg) {
    int q = nwg >> 3, r = nwg & 7;
    int xcd = bid & 7, idx = bid >> 3;
    return (xcd < r ? xcd * (q + 1) : r * (q + 1) + (xcd - r) * q) + idx;
}

// load 8 fp32 from a 92-float row at cols [c16*8, c16*8+8), zero-padded past 91
__device__ __forceinline__ void load8f(const float* __restrict__ rowp, int c16, float v[8]) {
    if (c16 < 11) {
        float4 a = *(const float4*)(rowp + c16 * 8);
        float4 b = *(const float4*)(rowp + c16 * 8 + 4);
        v[0]=a.x; v[1]=a.y; v[2]=a.z; v[3]=a.w; v[4]=b.x; v[5]=b.y; v[6]=b.z; v[7]=b.w;
    } else {
        float4 a = *(const float4*)(rowp + 88);
        v[0]=a.x; v[1]=a.y; v[2]=a.z; v[3]=a.w; v[4]=0.f; v[5]=0.f; v[6]=0.f; v[7]=0.f;
    }
}

// ---------------- sort infra: counting sort of edges by dst ----------------
__global__ __launch_bounds__(256) void hist_kernel(const int* __restrict__ ei,
                                                   int* __restrict__ bins)
{
    int e = blockIdx.x * 256 + threadIdx.x;
    if (e < N_EDGES) atomicAdd(&bins[ei[N_EDGES + e]], 1);
}

__global__ __launch_bounds__(1024) void scan_kernel(const int* __restrict__ bins,
                                                    int* __restrict__ cursor)
{
    __shared__ int tot[1024];
    const int t = threadIdx.x;
    const int C = (N_NODES + 1023) / 1024;
    const int i0 = t * C, i1 = min(i0 + C, N_NODES);
    int s = 0;
    for (int i = i0; i < i1; ++i) s += bins[i];
    tot[t] = s;
    __syncthreads();
    for (int off = 1; off < 1024; off <<= 1) {
        int v = (t >= off) ? tot[t - off] : 0;
        __syncthreads();
        tot[t] += v;
        __syncthreads();
    }
    int run = tot[t] - s;   // exclusive base
    for (int i = i0; i < i1; ++i) { cursor[i] = run; run += bins[i]; }
}

__global__ __launch_bounds__(256) void place_kernel(const int* __restrict__ ei,
                                                    int* __restrict__ cursor,
                                                    int* __restrict__ perm,
                                                    int* __restrict__ invp,
                                                    int* __restrict__ s_src,
                                                    int* __restrict__ s_dst)
{
    int e = blockIdx.x * 256 + threadIdx.x;
    if (e < N_EDGES) {
        int d = ei[N_EDGES + e];
        int pos = atomicAdd(&cursor[d], 1);
        perm[pos] = e;
        invp[e] = pos;
        s_dst[pos] = d;
        s_src[pos] = ei[e];
    }
}

// ---------------- one-time: scatter ea into dst-sorted f16 rows (coalesced read) ----------------
__global__ __launch_bounds__(256) void permute_ea16s(const float* __restrict__ ea,
                                                     const int* __restrict__ invp,
                                                     _Float16* __restrict__ ebf)
{
    long i = (long)blockIdx.x * 256 + threadIdx.x;
    if (i >= (long)N_EDGES * NEP) return;
    long e = i / NEP; int c = (int)(i - e * NEP);
    float v = (c < EF) ? ea[e * EF + c] : 0.0f;
    ebf[(size_t)invp[e] * NEP + c] = (_Float16)v;
}

// ---------------- merged weight conversion (all layers, node+edge+fc) ----------------
// blocks [0,432): node bf16 hi/lo; [432,576): edge f16 (hi only); [576,612): fc
__global__ __launch_bounds__(256) void convert_all(
    const float* __restrict__ Wf0, const float* __restrict__ Ws0,
    const float* __restrict__ Wf1, const float* __restrict__ Ws1,
    const float* __restrict__ Wf2, const float* __restrict__ Ws2,
    const float* __restrict__ fc1W,
    unsigned short* __restrict__ WcNh, unsigned short* __restrict__ WcNl,
    _Float16* __restrict__ WcEh,
    unsigned short* __restrict__ WcFh, unsigned short* __restrict__ WcFl)
{
    const int bid = blockIdx.x;
    if (bid < 432) {
        int l = bid / 144;
        int idx = (bid - l * 144) * 256 + threadIdx.x;
        if (idx >= 36864) return;
        const float* Wf = (l == 0) ? Wf0 : (l == 1) ? Wf1 : Wf2;
        const float* Ws = (l == 0) ? Ws0 : (l == 1) ? Ws1 : Ws2;
        int j    = idx & 7;
        int lane = (idx >> 3) & 63;
        int nt   = (idx >> 9) % 24;
        int ks   = idx / (24 * 512);
        int k = ks * 32 + ((lane >> 4) * 8) + j;
        int n = nt * 16 + (lane & 15);
        int t = n / 96, col = n % 96;
        float val = 0.f;
        if (k < 92 && col < 92) {
            const float* W = (t < 2) ? Wf : Ws;
            int rowoff = (t & 1) ? 92 : 0;
            val = W[(rowoff + k) * NF + col];
        }
        unsigned short hi = f2bf(val);
        size_t o = (size_t)l * 36864 + idx;
        WcNh[o] = hi;
        WcNl[o] = f2bf(val - bf2f(hi));
    } else if (bid < 576) {
        int b2 = bid - 432;
        int l = b2 / 48;
        int idx = (b2 - l * 48) * 256 + threadIdx.x;
        if (idx >= 12288) return;
        const float* Wf = (l == 0) ? Wf0 : (l == 1) ? Wf1 : Wf2;
        const float* Ws = (l == 0) ? Ws0 : (l == 1) ? Ws1 : Ws2;
        int j    = idx & 7;
        int lane = (idx >> 3) & 63;
        int nt   = (idx >> 9) % 12;
        int ks   = idx / (12 * 512);
        int k = ks * 32 + ((lane >> 4) * 8) + j;
        int n = nt * 16 + (lane & 15);
        float val = 0.f;
        if (k < EF) {
            if (n < 92)                  val = Wf[(184 + k) * NF + n];
            else if (n >= 96 && n < 188) val = Ws[(184 + k) * NF + (n - 96)];
        }
        WcEh[(size_t)l * 12288 + idx] = (_Float16)val;
    } else {
        int idx = (bid - 576) * 256 + threadIdx.x;
        if (idx >= WCF_ELEMS) return;
        int j    = idx & 7;
        int lane = (idx >> 3) & 63;
        int nt   = (idx >> 9) % 6;
        int ks   = idx / (6 * 512);
        int k = ks * 32 + ((lane >> 4) * 8) + j;
        int n = nt * 16 + (lane & 15);
        float val = (k < 92 && n < 92) ? fc1W[k * NF + n] : 0.f;
        unsigned short hi = f2bf(val);
        WcFh[idx] = hi;
        WcFl[idx] = f2bf(val - bf2f(hi));
    }
}

// ---------------- fused node GEMM ----------------
// Tables: Dh f16x2 {Pf+bf, Ps+bs}; Sh f16x2 {Qf, Qs}
template <int SMODE>
__global__ __launch_bounds__(384) void node_mfma_f(
    const float* __restrict__ in0, const float* __restrict__ in1,
    float* __restrict__ h_out,
    const unsigned short* __restrict__ Wh, const unsigned short* __restrict__ Wl,
    const float* __restrict__ bf, const float* __restrict__ bs,
    _Float16* __restrict__ Dh, _Float16* __restrict__ Sh,
    float* __restrict__ agg_zero)
{
    __shared__ char zz[2 * 64 * 256];     // hi | lo, 256B rows
    const int tid = threadIdx.x;
    const int n0 = blockIdx.x * 64;
    char* const zh = zz;
    char* const zl = zz + 64 * 256;

    for (int u = tid; u < 64 * 23; u += 384) {
        int e = u / 23, q = u - e * 23;
        int node = n0 + e;
        if (node < N_NODES)
            ((float4*)(agg_zero + (size_t)node * NF))[q] = make_float4(0.f, 0.f, 0.f, 0.f);
    }

    for (int u = tid; u < 64 * 16; u += 384) {
        int e = u >> 4, c16 = u & 15;
        int node = n0 + e;
        unsigned short th[8], tl[8];
        if (c16 < 12 && node < N_NODES) {
            float v[8];
            load8f(in0 + (size_t)node * NF, c16, v);
            if (SMODE == 1) {
                float v1[8];
                load8f(in1 + (size_t)node * NF, c16, v1);
#pragma unroll
                for (int j = 0; j < 8; ++j) v[j] = fast_silu(v[j] + v1[j]);
                float* hr = h_out + (size_t)node * NF;
                if (c16 < 11) {
                    *(float4*)(hr + c16 * 8)     = make_float4(v[0], v[1], v[2], v[3]);
                    *(float4*)(hr + c16 * 8 + 4) = make_float4(v[4], v[5], v[6], v[7]);
                } else {
                    *(float4*)(hr + 88) = make_float4(v[0], v[1], v[2], v[3]);
                }
            }
#pragma unroll
            for (int j = 0; j < 8; ++j) {
                unsigned short hi = f2bf(v[j]);
                th[j] = hi;
                tl[j] = f2bf(v[j] - bf2f(hi));
            }
        } else {
#pragma unroll
            for (int j = 0; j < 8; ++j) { th[j] = 0; tl[j] = 0; }
        }
        int byte = (c16 * 16) ^ ((e & 7) << 4);
        *(uint4*)(zh + e * 256 + byte) = *(uint4*)th;
        *(uint4*)(zl + e * 256 + byte) = *(uint4*)tl;
    }
    __syncthreads();

    const int w = tid >> 6, lane = tid & 63, lr = lane & 15, lg = lane >> 4;
    const int col = w * 16 + lr;
    const float bfv = (col < NF) ? bf[col] : 0.f;
    const float bsv = (col < NF) ? bs[col] : 0.f;

    float keepD[4][4], keepS[4][4];

    for (int ntx = 0; ntx < 4; ++ntx) {
        const int nt = w + 6 * ntx;      // table t == ntx, col fixed
        f32x4 acc[4];
#pragma unroll
        for (int m = 0; m < 4; ++m) acc[m] = (f32x4){0.f, 0.f, 0.f, 0.f};

#pragma unroll
        for (int ks = 0; ks < 3; ++ks) {
            bf16x8 bh = *(const bf16x8*)(Wh + ((size_t)(ks * 24 + nt) * 64 + lane) * 8);
            bf16x8 bl = *(const bf16x8*)(Wl + ((size_t)(ks * 24 + nt) * 64 + lane) * 8);
#pragma unroll
            for (int m = 0; m < 4; ++m) {
                int row  = m * 16 + lr;
                int byte = (ks * 64 + lg * 16) ^ ((row & 7) << 4);
                bf16x8 ah = *(const bf16x8*)(zh + row * 256 + byte);
                bf16x8 al = *(const bf16x8*)(zl + row * 256 + byte);
                acc[m] = __builtin_amdgcn_mfma_f32_16x16x32_bf16(ah, bh, acc[m], 0, 0, 0);
                acc[m] = __builtin_amdgcn_mfma_f32_16x16x32_bf16(ah, bl, acc[m], 0, 0, 0);
                acc[m] = __builtin_amdgcn_mfma_f32_16x16x32_bf16(al, bh, acc[m], 0, 0, 0);
            }
        }

        if (col < NF) {
#pragma unroll
            for (int m = 0; m < 4; ++m) {
#pragma unroll
                for (int r = 0; r < 4; ++r) {
                    int node = n0 + m * 16 + lg * 4 + r;
                    if (ntx == 0) keepD[m][r] = acc[m][r] + bfv;        // Pf+bf
                    else if (ntx == 1) keepS[m][r] = acc[m][r];         // Qf
                    else if (ntx == 2) {                                // Ps+bs -> write Dh
                        if (node < N_NODES) {
                            f16x2 hv;
                            hv[0] = (_Float16)keepD[m][r];
                            hv[1] = (_Float16)(acc[m][r] + bsv);
                            *(f16x2*)(Dh + ((size_t)node * 96 + col) * 2) = hv;
                        }
                    } else {                                            // Qs -> write Sh
                        if (node < N_NODES) {
                            f16x2 hv;
                            hv[0] = (_Float16)keepS[m][r];
                            hv[1] = (_Float16)acc[m][r];
                            *(f16x2*)(Sh + ((size_t)node * 96 + col) * 2) = hv;
                        }
                    }
                }
            }
        }
    }
}

// ---------------- edge kernel: 32 edges/block, single-W f16 GEMM, f16 tables ----------------
template <bool EB>
__global__ __launch_bounds__(384) void edge_mfma13(
    const int* __restrict__ s_src, const int* __restrict__ s_dst,
    const int* __restrict__ perm, const float* __restrict__ ea,
    const _Float16* __restrict__ ebf,
    const _Float16* __restrict__ Wh,
    const _Float16* __restrict__ Dh, const _Float16* __restrict__ Sh,
    float* __restrict__ agg, int nblk)
{
    __shared__ char zb[EBE * 128];    // z: 32 edges x 64 f16 (128B rows), swizzled
    __shared__ int sdst[EBE], ssrc[EBE], sperm[EBE];

    const int tid = threadIdx.x;
    const int bid = xcd_swz(blockIdx.x, nblk);
    const size_t e0 = (size_t)bid * EBE;

    if (tid < EBE) {
        ssrc[tid] = s_src[e0 + tid];
        sdst[tid] = s_dst[e0 + tid];
        if (!EB) sperm[tid] = perm[e0 + tid];
    }
    if (!EB) __syncthreads();

    if (tid < EBE * 8) {
        int e = tid >> 3, c16 = tid & 7;
        uint4 v = make_uint4(0u, 0u, 0u, 0u);
        if (EB) {
            if (c16 < 6) v = *(const uint4*)(ebf + (e0 + e) * NEP + c16 * 8);
        } else {
            if (c16 < 6) {
                const float* ear = ea + (size_t)sperm[e] * EF;
                _Float16 t[8];
#pragma unroll
                for (int jj = 0; jj < 8; ++jj) {
                    int cc = c16 * 8 + jj;
                    t[jj] = (_Float16)((cc < EF) ? ear[cc] : 0.0f);
                }
                v = *(uint4*)t;
            }
        }
        int byte = (c16 * 16) ^ ((e & 7) << 4);
        *(uint4*)(zb + e * 128 + byte) = v;
    }
    __syncthreads();

    const int w = tid >> 6, lane = tid & 63, lr = lane & 15, lg = lane >> 4;
    const int c = w * 16 + lr;

    // prefetch BEFORE MFMA: 8 random S half2 + 2 run-start D half2
    f16x2 sv[2][4];
    f16x2 dv0[2];
#pragma unroll
    for (int m = 0; m < 2; ++m) {
#pragma unroll
        for (int r = 0; r < 4; ++r)
            sv[m][r] = *(const f16x2*)(Sh + ((size_t)ssrc[m * 16 + lg * 4 + r] * 96 + c) * 2);
        dv0[m] = *(const f16x2*)(Dh + ((size_t)sdst[m * 16 + lg * 4] * 96 + c) * 2);
    }

    f32x4 accF[2], accS[2];
#pragma unroll
    for (int m = 0; m < 2; ++m) {
        accF[m] = (f32x4){0.f, 0.f, 0.f, 0.f};
        accS[m] = (f32x4){0.f, 0.f, 0.f, 0.f};
    }

#pragma unroll
    for (int ks = 0; ks < 2; ++ks) {
        f16x8 bF = *(const f16x8*)(Wh + ((size_t)(ks * 12 + w)     * 64 + lane) * 8);
        f16x8 bS = *(const f16x8*)(Wh + ((size_t)(ks * 12 + w + 6) * 64 + lane) * 8);
#pragma unroll
        for (int m = 0; m < 2; ++m) {
            int row  = m * 16 + lr;
            int byte = (ks * 64 + lg * 16) ^ ((row & 7) << 4);
            f16x8 a = *(const f16x8*)(zb + row * 128 + byte);
            accF[m] = __builtin_amdgcn_mfma_f32_16x16x32_f16(a, bF, accF[m], 0, 0, 0);
            accS[m] = __builtin_amdgcn_mfma_f32_16x16x32_f16(a, bS, accS[m], 0, 0, 0);
        }
    }

    if (c < NF) {
#pragma unroll
        for (int m = 0; m < 2; ++m) {
            const int eb0 = m * 16 + lg * 4;
            int prev = sdst[eb0];
            float dvx = (float)dv0[m][0], dvy = (float)dv0[m][1];
            float accum = 0.f;
#pragma unroll
            for (int r = 0; r < 4; ++r) {
                int dst = sdst[eb0 + r];
                if (dst != prev) {
                    atomicAdd(&agg[(size_t)prev * NF + c], accum);
                    accum = 0.f;
                    prev = dst;
                    f16x2 hv = *(const f16x2*)(Dh + ((size_t)dst * 96 + c) * 2);
                    dvx = (float)hv[0]; dvy = (float)hv[1];
                }
                float f = accF[m][r] + dvx + (float)sv[m][r][0];
                float s = accS[m][r] + dvy + (float)sv[m][r][1];
                accum += fast_sigmoid(f) * fast_softplus(s);
            }
            atomicAdd(&agg[(size_t)prev * NF + c], accum);
        }
    }
}

// ---------------- fused fc1 via split-bf16 MFMA ----------------
template <int SMODE, bool POOL>
__global__ __launch_bounds__(384) void fc_mfma_f(
    const float* __restrict__ in0, const float* __restrict__ in1,
    const unsigned short* __restrict__ Wh, const unsigned short* __restrict__ Wl,
    const float* __restrict__ b, float* __restrict__ outp)
{
    __shared__ char zz[2 * 64 * 256];
    const int tid = threadIdx.x;
    const int n0 = blockIdx.x * 64;
    char* const zh = zz;
    char* const zl = zz + 64 * 256;

    for (int u = tid; u < 64 * 16; u += 384) {
        int e = u >> 4, c16 = u & 15;
        int node = n0 + e;
        unsigned short th[8], tl[8];
        if (c16 < 12 && node < N_NODES) {
            float v[8];
            load8f(in0 + (size_t)node * NF, c16, v);
            if (SMODE == 1) {
                float v1[8];
                load8f(in1 + (size_t)node * NF, c16, v1);
#pragma unroll
                for (int j = 0; j < 8; ++j) v[j] = fast_silu(v[j] + v1[j]);
            }
#pragma unroll
            for (int j = 0; j < 8; ++j) {
                unsigned short hi = f2bf(v[j]);
                th[j] = hi;
                tl[j] = f2bf(v[j] - bf2f(hi));
            }
        } else {
#pragma unroll
            for (int j = 0; j < 8; ++j) { th[j] = 0; tl[j] = 0; }
        }
        int byte = (c16 * 16) ^ ((e & 7) << 4);
        *(uint4*)(zh + e * 256 + byte) = *(uint4*)th;
        *(uint4*)(zl + e * 256 + byte) = *(uint4*)tl;
    }
    __syncthreads();

    const int w = tid >> 6, lane = tid & 63, lr = lane & 15, lg = lane >> 4;
    const int col = w * 16 + lr;
    const float bv = (col < NF) ? b[col] : 0.f;

    f32x4 acc[4];
#pragma unroll
    for (int m = 0; m < 4; ++m) acc[m] = (f32x4){0.f, 0.f, 0.f, 0.f};

#pragma unroll
    for (int ks = 0; ks < 3; ++ks) {
        bf16x8 bh = *(const bf16x8*)(Wh + ((size_t)(ks * 6 + w) * 64 + lane) * 8);
        bf16x8 bl = *(const bf16x8*)(Wl + ((size_t)(ks * 6 + w) * 64 + lane) * 8);
#pragma unroll
        for (int m = 0; m < 4; ++m) {
            int row  = m * 16 + lr;
            int byte = (ks * 64 + lg * 16) ^ ((row & 7) << 4);
            bf16x8 ah = *(const bf16x8*)(zh + row * 256 + byte);
            bf16x8 al = *(const bf16x8*)(zl + row * 256 + byte);
            acc[m] = __builtin_amdgcn_mfma_f32_16x16x32_bf16(ah, bh, acc[m], 0, 0, 0);
            acc[m] = __builtin_amdgcn_mfma_f32_16x16x32_bf16(ah, bl, acc[m], 0, 0, 0);
            acc[m] = __builtin_amdgcn_mfma_f32_16x16x32_bf16(al, bh, acc[m], 0, 0, 0);
        }
    }

    if (POOL) {
        float psum = 0.f;
#pragma unroll
        for (int m = 0; m < 4; ++m)
#pragma unroll
            for (int r = 0; r < 4; ++r) {
                int node = n0 + m * 16 + lg * 4 + r;
                if (node < N_NODES && col < NF)
                    psum += fast_silu(acc[m][r] + bv);
            }
        psum += __shfl_down(psum, 32);
        psum += __shfl_down(psum, 16);
        if (lg == 0 && col < NF) atomicAdd(&outp[col], psum);
    } else {
#pragma unroll
        for (int m = 0; m < 4; ++m)
#pragma unroll
            for (int r = 0; r < 4; ++r) {
                int node = n0 + m * 16 + lg * 4 + r;
                if (node < N_NODES && col < NF)
                    outp[(size_t)node * NF + col] = fast_silu(acc[m][r] + bv);
            }
    }
}

// ---------------- split MLP head ----------------
__global__ __launch_bounds__(128) void mlp_a(const float* __restrict__ pooled,
                                             const float* __restrict__ glob,
                                             const float* __restrict__ W2,
                                             const float* __restrict__ b2,
                                             float* __restrict__ g1)
{
    __shared__ float vin[NF + GF];
    const int t = threadIdx.x;
    for (int i = t; i < NF + GF; i += 128)
        vin[i] = (i < NF) ? pooled[i] * (1.0f / (float)N_NODES) : glob[i - NF];
    __syncthreads();
    const int col = blockIdx.x * 128 + t;
    float a = b2[col];
    for (int k = 0; k < NF + GF; ++k) a = fmaf(vin[k], W2[k * 1024 + col], a);
    g1[col] = fast_silu(a);
}

__global__ __launch_bounds__(128) void mlp_b(const float* __restrict__ g1,
                                             const float* __restrict__ W3,
                                             const float* __restrict__ b3,
                                             float* __restrict__ g2)
{
    __shared__ float vin[1024];
    const int t = threadIdx.x;
    for (int i = t; i < 1024; i += 128) vin[i] = g1[i];
    __syncthreads();
    const int col = blockIdx.x * 128 + t;
    float a = b3[col];
    for (int k = 0; k < 1024; ++k) a = fmaf(vin[k], W3[k * 512 + col], a);
    g2[col] = fast_silu(a);
}

__global__ __launch_bounds__(512) void mlp_c(const float* __restrict__ g2,
    const float* __restrict__ W4, const float* __restrict__ b4,
    const float* __restrict__ W5, const float* __restrict__ b5,
    const float* __restrict__ W6, const float* __restrict__ b6,
    const float* __restrict__ W7, const float* __restrict__ b7,
    float* __restrict__ out)
{
    __shared__ float va[512], vb[256];
    const int t = threadIdx.x;
    va[t] = g2[t];
    __syncthreads();

    if (t < 256) { // fc4: 512 -> 256
        float a = b4[t];
        for (int k = 0; k < 512; ++k) a = fmaf(va[k], W4[k * 256 + t], a);
        vb[t] = fast_silu(a);
    }
    __syncthreads();
    if (t < 128) { // fc5: 256 -> 128
        float a = b5[t];
        for (int k = 0; k < 256; ++k) a = fmaf(vb[k], W5[k * 128 + t], a);
        va[t] = fast_silu(a);
    }
    __syncthreads();
    if (t < 64) { // fc6: 128 -> 64
        float a = b6[t];
        for (int k = 0; k < 128; ++k) a = fmaf(va[k], W6[k * 64 + t], a);
        vb[t] = fast_silu(a);
    }
    __syncthreads();
    if (t < 64) { // fc7: 64 -> 1
        float p = vb[t] * W7[t];
        for (int off = 32; off; off >>= 1) p += __shfl_down(p, off);
        if (t == 0) out[0] = p + b7[0];
    }
}

// ---------------- launch ----------------
extern "C" void kernel_launch(void* const* d_in, const int* in_sizes, int n_in,
                              void* d_out, int out_size, void* d_ws, size_t ws_size,
                              hipStream_t stream)
{
    (void)in_sizes; (void)n_in; (void)out_size;

    const float* x    = (const float*)d_in[0];
    const int*   ei   = (const int*)d_in[1];
    const float* ea   = (const float*)d_in[2];
    const float* glob = (const float*)d_in[3];
    const float* cWf[3] = {(const float*)d_in[5],  (const float*)d_in[9],  (const float*)d_in[13]};
    const float* cbf[3] = {(const float*)d_in[6],  (const float*)d_in[10], (const float*)d_in[14]};
    const float* cWs[3] = {(const float*)d_in[7],  (const float*)d_in[11], (const float*)d_in[15]};
    const float* cbs[3] = {(const float*)d_in[8],  (const float*)d_in[12], (const float*)d_in[16]};
    const float* fc1W = (const float*)d_in[17]; const float* fc1b = (const float*)d_in[18];
    const float* W2 = (const float*)d_in[19];   const float* b2 = (const float*)d_in[20];
    const float* W3 = (const float*)d_in[21];   const float* b3 = (const float*)d_in[22];
    const float* W4 = (const float*)d_in[23];   const float* b4 = (const float*)d_in[24];
    const float* W5 = (const float*)d_in[25];   const float* b5 = (const float*)d_in[26];
    const float* W6 = (const float*)d_in[27];   const float* b6 = (const float*)d_in[28];
    const float* W7 = (const float*)d_in[29];   const float* b7 = (const float*)d_in[30];
    float* out = (float*)d_out;

    const size_t H = (size_t)N_NODES * NF;
    float* h1   = (float*)d_ws;                              // fp32 node state
    float* h2   = h1 + H;
    float* aggA = h2 + H;
    float* aggB = aggA + H;
    float* pooled = aggB + H;                                // 128
    float* g1 = pooled + 128;                                // 1024
    float* g2 = g1 + 1024;                                   // 512
    unsigned short* WcNh = (unsigned short*)(g2 + 512);      // 3*36864 bf16
    unsigned short* WcNl = WcNh + 3 * (size_t)36864;
    unsigned short* WcFh = WcNl + 3 * (size_t)36864;         // 9216 bf16
    unsigned short* WcFl = WcFh + (size_t)WCF_ELEMS;
    _Float16* WcEh = (_Float16*)(WcFl + (size_t)WCF_ELEMS);  // 3*12288 f16
    _Float16* Dh = WcEh + 3 * (size_t)12288;                 // N*96 f16x2
    _Float16* Sh = Dh + (size_t)2 * N_NODES * 96;            // N*96 f16x2
    int* bins   = (int*)(Sh + (size_t)2 * N_NODES * 96);
    int* cursor = bins + N_NODES;
    int* perm   = cursor + N_NODES;
    int* invp   = perm + N_EDGES;
    int* s_src  = invp + N_EDGES;
    int* s_dst  = s_src + N_EDGES;
    _Float16* ebf = (_Float16*)(s_dst + N_EDGES);            // E*48 f16 (sorted)
    const size_t need_full = (size_t)((char*)(ebf + (size_t)N_EDGES * NEP) - (char*)d_ws);
    const bool use_eb = ws_size >= need_full;

    const int nEdgeBlocks = N_EDGES / EBE;                   // 25000
    const int nNodeBlocks = (N_NODES + 63) / 64;             // 782

    // one-time: sort edges by dst, scatter ea to sorted f16, convert weights
    hipMemsetAsync(bins, 0, N_NODES * sizeof(int), stream);
    hist_kernel<<<(N_EDGES + 255) / 256, 256, 0, stream>>>(ei, bins);
    scan_kernel<<<1, 1024, 0, stream>>>(bins, cursor);
    place_kernel<<<(N_EDGES + 255) / 256, 256, 0, stream>>>(ei, cursor, perm, invp, s_src, s_dst);
    if (use_eb)
        permute_ea16s<<<(int)(((long)N_EDGES * NEP + 255) / 256), 256, 0, stream>>>(ea, invp, ebf);
    convert_all<<<612, 256, 0, stream>>>(cWf[0], cWs[0], cWf[1], cWs[1], cWf[2], cWs[2],
                                         fc1W, WcNh, WcNl, WcEh, WcFh, WcFl);

    // conv layers (fused: silu+residual+stage+agg-zero inside node_mfma_f)
    node_mfma_f<0><<<nNodeBlocks, 384, 0, stream>>>(x, nullptr, nullptr,
        WcNh, WcNl, cbf[0], cbs[0], Dh, Sh, aggA);
    if (use_eb)
        edge_mfma13<true><<<nEdgeBlocks, 384, 0, stream>>>(s_src, s_dst, perm, ea, ebf,
            WcEh, Dh, Sh, aggA, nEdgeBlocks);
    else
        edge_mfma13<false><<<nEdgeBlocks, 384, 0, stream>>>(s_src, s_dst, perm, ea, ebf,
            WcEh, Dh, Sh, aggA, nEdgeBlocks);

    node_mfma_f<1><<<nNodeBlocks, 384, 0, stream>>>(x, aggA, h1,
        WcNh + (size_t)36864, WcNl + (size_t)36864, cbf[1], cbs[1], Dh, Sh, aggB);
    if (use_eb)
        edge_mfma13<true><<<nEdgeBlocks, 384, 0, stream>>>(s_src, s_dst, perm, ea, ebf,
            WcEh + (size_t)12288, Dh, Sh, aggB, nEdgeBlocks);
    else
        edge_mfma13<false><<<nEdgeBlocks, 384, 0, stream>>>(s_src, s_dst, perm, ea, ebf,
            WcEh + (size_t)12288, Dh, Sh, aggB, nEdgeBlocks);

    node_mfma_f<1><<<nNodeBlocks, 384, 0, stream>>>(h1, aggB, h2,
        WcNh + (size_t)2 * 36864, WcNl + (size_t)2 * 36864, cbf[2], cbs[2], Dh, Sh, aggA);
    if (use_eb)
        edge_mfma13<true><<<nEdgeBlocks, 384, 0, stream>>>(s_src, s_dst, perm, ea, ebf,
            WcEh + (size_t)2 * 12288, Dh, Sh, aggA, nEdgeBlocks);
    else
        edge_mfma13<false><<<nEdgeBlocks, 384, 0, stream>>>(s_src, s_dst, perm, ea, ebf,
            WcEh + (size_t)2 * 12288, Dh, Sh, aggA, nEdgeBlocks);

    // fc1 #1: stage silu(h2 + aggA), write fp32 -> aggB
    fc_mfma_f<1, false><<<nNodeBlocks, 384, 0, stream>>>(h2, aggA, WcFh, WcFl, fc1b, aggB);
    // fc1 #2: stage aggB, fused mean-pool into pooled
    hipMemsetAsync(pooled, 0, NF * sizeof(float), stream);
    fc_mfma_f<0, true><<<nNodeBlocks, 384, 0, stream>>>(aggB, nullptr, WcFh, WcFl, fc1b, pooled);

    // MLP head (split)
    mlp_a<<<8, 128, 0, stream>>>(pooled, glob, W2, b2, g1);
    mlp_b<<<4, 128, 0, stream>>>(g1, W3, b3, g2);
    mlp_c<<<1, 512, 0, stream>>>(g2, W4, b4, W5, b5, W6, b6, W7, b7, out);
}

// Round 16
// 946.756 us; speedup vs baseline: 1.4291x; 1.3003x over previous
//
#include <hip/hip_runtime.h>
#include <math.h>

// ---------------- problem constants ----------------
#define N_NODES 50000
#define N_EDGES 800000
#define NF 92           // node features
#define EF 41           // edge features
#define GF 180          // global attr
#define NEP 48          // padded f16 edge_attr row (dst-sorted)
#define EBE 32          // edges per block in edge kernel

#define WCF_ELEMS (3 * 6 * 64 * 8)    // fc1 weights (bf16 hi/lo)

typedef __attribute__((ext_vector_type(8))) short bf16x8;
typedef __attribute__((ext_vector_type(8))) _Float16 f16x8;
typedef __attribute__((ext_vector_type(2))) _Float16 f16x2;
typedef __attribute__((ext_vector_type(4))) float f32x4;

#define L2E 1.44269504f
#define LN2 0.69314718f

__device__ __forceinline__ float fast_sigmoid(float x) {
    return __builtin_amdgcn_rcpf(1.0f + __builtin_amdgcn_exp2f(-x * L2E));
}
__device__ __forceinline__ float fast_softplus(float x) {
    float t = __builtin_amdgcn_exp2f(-fabsf(x) * L2E);
    return fmaxf(x, 0.0f) + __builtin_amdgcn_logf(1.0f + t) * LN2;
}
__device__ __forceinline__ float fast_silu(float x) { return x * fast_sigmoid(x); }

__device__ __forceinline__ unsigned short f2bf(float x) {
    union { float f; unsigned u; } v; v.f = x;
    unsigned r = v.u + 0x7FFF + ((v.u >> 16) & 1);   // RNE
    return (unsigned short)(r >> 16);
}
__device__ __forceinline__ float bf2f(unsigned short h) {
    union { unsigned u; float f; } v; v.u = ((unsigned)h) << 16; return v.f;
}

// bijective XCD-aware block swizzle (m204 variant)
__device__ __forceinline__ int xcd_swz(int bid, int nwg) {
    int q = nwg >> 3, r = nwg & 7;
    int xcd = bid & 7, idx = bid >> 3;
    return (xcd < r ? xcd * (q + 1) : r * (q + 1) + (xcd - r) * q) + idx;
}

// load 8 fp32 from a 92-float row at cols [c16*8, c16*8+8), zero-padded past 91
__device__ __forceinline__ void load8f(const float* __restrict__ rowp, int c16, float v[8]) {
    if (c16 < 11) {
        float4 a = *(const float4*)(rowp + c16 * 8);
        float4 b = *(const float4*)(rowp + c16 * 8 + 4);
        v[0]=a.x; v[1]=a.y; v[2]=a.z; v[3]=a.w; v[4]=b.x; v[5]=b.y; v[6]=b.z; v[7]=b.w;
    } else {
        float4 a = *(const float4*)(rowp + 88);
        v[0]=a.x; v[1]=a.y; v[2]=a.z; v[3]=a.w; v[4]=0.f; v[5]=0.f; v[6]=0.f; v[7]=0.f;
    }
}

// ---------------- sort infra: counting sort of edges by dst ----------------
__global__ __launch_bounds__(256) void hist_kernel(const int* __restrict__ ei,
                                                   int* __restrict__ bins)
{
    int e = blockIdx.x * 256 + threadIdx.x;
    if (e < N_EDGES) atomicAdd(&bins[ei[N_EDGES + e]], 1);
}

__global__ __launch_bounds__(1024) void scan_kernel(const int* __restrict__ bins,
                                                    int* __restrict__ cursor)
{
    __shared__ int tot[1024];
    const int t = threadIdx.x;
    const int C = (N_NODES + 1023) / 1024;
    const int i0 = t * C, i1 = min(i0 + C, N_NODES);
    int s = 0;
    for (int i = i0; i < i1; ++i) s += bins[i];
    tot[t] = s;
    __syncthreads();
    for (int off = 1; off < 1024; off <<= 1) {
        int v = (t >= off) ? tot[t - off] : 0;
        __syncthreads();
        tot[t] += v;
        __syncthreads();
    }
    int run = tot[t] - s;   // exclusive base
    for (int i = i0; i < i1; ++i) { cursor[i] = run; run += bins[i]; }
}

// place with slot remap: sorted position q=(grp*32+off) is stored at slot
// grp*32 + m*16 + lg*4 + r where off = lg*8 + m*4 + r. This makes each
// epilogue lane (lg) own 8 CONSECUTIVE dst-sorted edges -> longer merge runs.
__global__ __launch_bounds__(256) void place_kernel(const int* __restrict__ ei,
                                                    int* __restrict__ cursor,
                                                    int* __restrict__ perm,
                                                    int* __restrict__ invp,
                                                    int* __restrict__ s_src,
                                                    int* __restrict__ s_dst)
{
    int e = blockIdx.x * 256 + threadIdx.x;
    if (e < N_EDGES) {
        int d = ei[N_EDGES + e];
        int pos = atomicAdd(&cursor[d], 1);
        int grp = pos >> 5, off = pos & 31;
        int lg = off >> 3, m = (off >> 2) & 1, r = off & 3;
        int slot = (grp << 5) + m * 16 + lg * 4 + r;
        perm[slot] = e;
        invp[e] = slot;
        s_dst[slot] = d;
        s_src[slot] = ei[e];
    }
}

// ---------------- one-time: scatter ea into slot-ordered f16 rows ----------------
__global__ __launch_bounds__(256) void permute_ea16s(const float* __restrict__ ea,
                                                     const int* __restrict__ invp,
                                                     _Float16* __restrict__ ebf)
{
    long i = (long)blockIdx.x * 256 + threadIdx.x;
    if (i >= (long)N_EDGES * NEP) return;
    long e = i / NEP; int c = (int)(i - e * NEP);
    float v = (c < EF) ? ea[e * EF + c] : 0.0f;
    ebf[(size_t)invp[e] * NEP + c] = (_Float16)v;
}

// ---------------- merged weight conversion (all layers, node+edge+fc) ----------------
__global__ __launch_bounds__(256) void convert_all(
    const float* __restrict__ Wf0, const float* __restrict__ Ws0,
    const float* __restrict__ Wf1, const float* __restrict__ Ws1,
    const float* __restrict__ Wf2, const float* __restrict__ Ws2,
    const float* __restrict__ fc1W,
    unsigned short* __restrict__ WcNh, unsigned short* __restrict__ WcNl,
    _Float16* __restrict__ WcEh,
    unsigned short* __restrict__ WcFh, unsigned short* __restrict__ WcFl)
{
    const int bid = blockIdx.x;
    if (bid < 432) {
        int l = bid / 144;
        int idx = (bid - l * 144) * 256 + threadIdx.x;
        if (idx >= 36864) return;
        const float* Wf = (l == 0) ? Wf0 : (l == 1) ? Wf1 : Wf2;
        const float* Ws = (l == 0) ? Ws0 : (l == 1) ? Ws1 : Ws2;
        int j    = idx & 7;
        int lane = (idx >> 3) & 63;
        int nt   = (idx >> 9) % 24;
        int ks   = idx / (24 * 512);
        int k = ks * 32 + ((lane >> 4) * 8) + j;
        int n = nt * 16 + (lane & 15);
        int t = n / 96, col = n % 96;
        float val = 0.f;
        if (k < 92 && col < 92) {
            const float* W = (t < 2) ? Wf : Ws;
            int rowoff = (t & 1) ? 92 : 0;
            val = W[(rowoff + k) * NF + col];
        }
        unsigned short hi = f2bf(val);
        size_t o = (size_t)l * 36864 + idx;
        WcNh[o] = hi;
        WcNl[o] = f2bf(val - bf2f(hi));
    } else if (bid < 576) {
        int b2 = bid - 432;
        int l = b2 / 48;
        int idx = (b2 - l * 48) * 256 + threadIdx.x;
        if (idx >= 12288) return;
        const float* Wf = (l == 0) ? Wf0 : (l == 1) ? Wf1 : Wf2;
        const float* Ws = (l == 0) ? Ws0 : (l == 1) ? Ws1 : Ws2;
        int j    = idx & 7;
        int lane = (idx >> 3) & 63;
        int nt   = (idx >> 9) % 12;
        int ks   = idx / (12 * 512);
        int k = ks * 32 + ((lane >> 4) * 8) + j;
        int n = nt * 16 + (lane & 15);
        float val = 0.f;
        if (k < EF) {
            if (n < 92)                  val = Wf[(184 + k) * NF + n];
            else if (n >= 96 && n < 188) val = Ws[(184 + k) * NF + (n - 96)];
        }
        WcEh[(size_t)l * 12288 + idx] = (_Float16)val;
    } else {
        int idx = (bid - 576) * 256 + threadIdx.x;
        if (idx >= WCF_ELEMS) return;
        int j    = idx & 7;
        int lane = (idx >> 3) & 63;
        int nt   = (idx >> 9) % 6;
        int ks   = idx / (6 * 512);
        int k = ks * 32 + ((lane >> 4) * 8) + j;
        int n = nt * 16 + (lane & 15);
        float val = (k < 92 && n < 92) ? fc1W[k * NF + n] : 0.f;
        unsigned short hi = f2bf(val);
        WcFh[idx] = hi;
        WcFl[idx] = f2bf(val - bf2f(hi));
    }
}

// ---------------- fused node GEMM ----------------
// Tables: Dh f16x2 {Pf+bf, Ps+bs}; Sh f16x2 {Qf, Qs}
template <int SMODE>
__global__ __launch_bounds__(384) void node_mfma_f(
    const float* __restrict__ in0, const float* __restrict__ in1,
    float* __restrict__ h_out,
    const unsigned short* __restrict__ Wh, const unsigned short* __restrict__ Wl,
    const float* __restrict__ bf, const float* __restrict__ bs,
    _Float16* __restrict__ Dh, _Float16* __restrict__ Sh,
    float* __restrict__ agg_zero)
{
    __shared__ char zz[2 * 64 * 256];     // hi | lo, 256B rows
    const int tid = threadIdx.x;
    const int n0 = blockIdx.x * 64;
    char* const zh = zz;
    char* const zl = zz + 64 * 256;

    for (int u = tid; u < 64 * 23; u += 384) {
        int e = u / 23, q = u - e * 23;
        int node = n0 + e;
        if (node < N_NODES)
            ((float4*)(agg_zero + (size_t)node * NF))[q] = make_float4(0.f, 0.f, 0.f, 0.f);
    }

    for (int u = tid; u < 64 * 16; u += 384) {
        int e = u >> 4, c16 = u & 15;
        int node = n0 + e;
        unsigned short th[8], tl[8];
        if (c16 < 12 && node < N_NODES) {
            float v[8];
            load8f(in0 + (size_t)node * NF, c16, v);
            if (SMODE == 1) {
                float v1[8];
                load8f(in1 + (size_t)node * NF, c16, v1);
#pragma unroll
                for (int j = 0; j < 8; ++j) v[j] = fast_silu(v[j] + v1[j]);
                float* hr = h_out + (size_t)node * NF;
                if (c16 < 11) {
                    *(float4*)(hr + c16 * 8)     = make_float4(v[0], v[1], v[2], v[3]);
                    *(float4*)(hr + c16 * 8 + 4) = make_float4(v[4], v[5], v[6], v[7]);
                } else {
                    *(float4*)(hr + 88) = make_float4(v[0], v[1], v[2], v[3]);
                }
            }
#pragma unroll
            for (int j = 0; j < 8; ++j) {
                unsigned short hi = f2bf(v[j]);
                th[j] = hi;
                tl[j] = f2bf(v[j] - bf2f(hi));
            }
        } else {
#pragma unroll
            for (int j = 0; j < 8; ++j) { th[j] = 0; tl[j] = 0; }
        }
        int byte = (c16 * 16) ^ ((e & 7) << 4);
        *(uint4*)(zh + e * 256 + byte) = *(uint4*)th;
        *(uint4*)(zl + e * 256 + byte) = *(uint4*)tl;
    }
    __syncthreads();

    const int w = tid >> 6, lane = tid & 63, lr = lane & 15, lg = lane >> 4;
    const int col = w * 16 + lr;
    const float bfv = (col < NF) ? bf[col] : 0.f;
    const float bsv = (col < NF) ? bs[col] : 0.f;

    float keepD[4][4], keepS[4][4];

    for (int ntx = 0; ntx < 4; ++ntx) {
        const int nt = w + 6 * ntx;      // table t == ntx, col fixed
        f32x4 acc[4];
#pragma unroll
        for (int m = 0; m < 4; ++m) acc[m] = (f32x4){0.f, 0.f, 0.f, 0.f};

#pragma unroll
        for (int ks = 0; ks < 3; ++ks) {
            bf16x8 bh = *(const bf16x8*)(Wh + ((size_t)(ks * 24 + nt) * 64 + lane) * 8);
            bf16x8 bl = *(const bf16x8*)(Wl + ((size_t)(ks * 24 + nt) * 64 + lane) * 8);
#pragma unroll
            for (int m = 0; m < 4; ++m) {
                int row  = m * 16 + lr;
                int byte = (ks * 64 + lg * 16) ^ ((row & 7) << 4);
                bf16x8 ah = *(const bf16x8*)(zh + row * 256 + byte);
                bf16x8 al = *(const bf16x8*)(zl + row * 256 + byte);
                acc[m] = __builtin_amdgcn_mfma_f32_16x16x32_bf16(ah, bh, acc[m], 0, 0, 0);
                acc[m] = __builtin_amdgcn_mfma_f32_16x16x32_bf16(ah, bl, acc[m], 0, 0, 0);
                acc[m] = __builtin_amdgcn_mfma_f32_16x16x32_bf16(al, bh, acc[m], 0, 0, 0);
            }
        }

        if (col < NF) {
#pragma unroll
            for (int m = 0; m < 4; ++m) {
#pragma unroll
                for (int r = 0; r < 4; ++r) {
                    int node = n0 + m * 16 + lg * 4 + r;
                    if (ntx == 0) keepD[m][r] = acc[m][r] + bfv;        // Pf+bf
                    else if (ntx == 1) keepS[m][r] = acc[m][r];         // Qf
                    else if (ntx == 2) {                                // Ps+bs -> write Dh
                        if (node < N_NODES) {
                            f16x2 hv;
                            hv[0] = (_Float16)keepD[m][r];
                            hv[1] = (_Float16)(acc[m][r] + bsv);
                            *(f16x2*)(Dh + ((size_t)node * 96 + col) * 2) = hv;
                        }
                    } else {                                            // Qs -> write Sh
                        if (node < N_NODES) {
                            f16x2 hv;
                            hv[0] = (_Float16)keepS[m][r];
                            hv[1] = (_Float16)acc[m][r];
                            *(f16x2*)(Sh + ((size_t)node * 96 + col) * 2) = hv;
                        }
                    }
                }
            }
        }
    }
}

// ---------------- edge kernel: slot-permuted edges, cross-m merged atomics ----------------
template <bool EB>
__global__ __launch_bounds__(384) void edge_mfma14(
    const int* __restrict__ s_src, const int* __restrict__ s_dst,
    const int* __restrict__ perm, const float* __restrict__ ea,
    const _Float16* __restrict__ ebf,
    const _Float16* __restrict__ Wh,
    const _Float16* __restrict__ Dh, const _Float16* __restrict__ Sh,
    float* __restrict__ agg, int nblk)
{
    __shared__ char zb[EBE * 128];    // z: 32 edges x 64 f16 (128B rows), swizzled
    __shared__ int sdst[EBE], ssrc[EBE], sperm[EBE];

    const int tid = threadIdx.x;
    const int bid = xcd_swz(blockIdx.x, nblk);
    const size_t e0 = (size_t)bid * EBE;

    if (tid < EBE) {
        ssrc[tid] = s_src[e0 + tid];
        sdst[tid] = s_dst[e0 + tid];
        if (!EB) sperm[tid] = perm[e0 + tid];
    }
    if (!EB) __syncthreads();

    if (tid < EBE * 8) {
        int e = tid >> 3, c16 = tid & 7;
        uint4 v = make_uint4(0u, 0u, 0u, 0u);
        if (EB) {
            if (c16 < 6) v = *(const uint4*)(ebf + (e0 + e) * NEP + c16 * 8);
        } else {
            if (c16 < 6) {
                const float* ear = ea + (size_t)sperm[e] * EF;
                _Float16 t[8];
#pragma unroll
                for (int jj = 0; jj < 8; ++jj) {
                    int cc = c16 * 8 + jj;
                    t[jj] = (_Float16)((cc < EF) ? ear[cc] : 0.0f);
                }
                v = *(uint4*)t;
            }
        }
        int byte = (c16 * 16) ^ ((e & 7) << 4);
        *(uint4*)(zb + e * 128 + byte) = v;
    }
    __syncthreads();

    const int w = tid >> 6, lane = tid & 63, lr = lane & 15, lg = lane >> 4;
    const int c = w * 16 + lr;

    // prefetch BEFORE MFMA: 8 random S half2 + 1 run-start D half2
    // (lane's 8 edges are q = lg*8..lg*8+7 in dst-sorted order)
    f16x2 sv[2][4];
    f16x2 dv0;
#pragma unroll
    for (int m = 0; m < 2; ++m)
#pragma unroll
        for (int r = 0; r < 4; ++r)
            sv[m][r] = *(const f16x2*)(Sh + ((size_t)ssrc[m * 16 + lg * 4 + r] * 96 + c) * 2);
    dv0 = *(const f16x2*)(Dh + ((size_t)sdst[lg * 4] * 96 + c) * 2);

    f32x4 accF[2], accS[2];
#pragma unroll
    for (int m = 0; m < 2; ++m) {
        accF[m] = (f32x4){0.f, 0.f, 0.f, 0.f};
        accS[m] = (f32x4){0.f, 0.f, 0.f, 0.f};
    }

#pragma unroll
    for (int ks = 0; ks < 2; ++ks) {
        f16x8 bF = *(const f16x8*)(Wh + ((size_t)(ks * 12 + w)     * 64 + lane) * 8);
        f16x8 bS = *(const f16x8*)(Wh + ((size_t)(ks * 12 + w + 6) * 64 + lane) * 8);
#pragma unroll
        for (int m = 0; m < 2; ++m) {
            int row  = m * 16 + lr;
            int byte = (ks * 64 + lg * 16) ^ ((row & 7) << 4);
            f16x8 a = *(const f16x8*)(zb + row * 128 + byte);
            accF[m] = __builtin_amdgcn_mfma_f32_16x16x32_f16(a, bF, accF[m], 0, 0, 0);
            accS[m] = __builtin_amdgcn_mfma_f32_16x16x32_f16(a, bS, accS[m], 0, 0, 0);
        }
    }

    // epilogue: f/s = R + D[dst] + S[src]; merge atomics over the lane's
    // 8 consecutive sorted edges (carry run state across m)
    if (c < NF) {
        int prev = sdst[lg * 4];
        float dvx = (float)dv0[0], dvy = (float)dv0[1];
        float accum = 0.f;
#pragma unroll
        for (int m = 0; m < 2; ++m) {
            const int eb0 = m * 16 + lg * 4;
#pragma unroll
            for (int r = 0; r < 4; ++r) {
                int dst = sdst[eb0 + r];
                if (dst != prev) {
                    atomicAdd(&agg[(size_t)prev * NF + c], accum);
                    accum = 0.f;
                    prev = dst;
                    f16x2 hv = *(const f16x2*)(Dh + ((size_t)dst * 96 + c) * 2);
                    dvx = (float)hv[0]; dvy = (float)hv[1];
                }
                float f = accF[m][r] + dvx + (float)sv[m][r][0];
                float s = accS[m][r] + dvy + (float)sv[m][r][1];
                accum += fast_sigmoid(f) * fast_softplus(s);
            }
        }
        atomicAdd(&agg[(size_t)prev * NF + c], accum);
    }
}

// ---------------- fused fc1 via split-bf16 MFMA ----------------
template <int SMODE, bool POOL>
__global__ __launch_bounds__(384) void fc_mfma_f(
    const float* __restrict__ in0, const float* __restrict__ in1,
    const unsigned short* __restrict__ Wh, const unsigned short* __restrict__ Wl,
    const float* __restrict__ b, float* __restrict__ outp)
{
    __shared__ char zz[2 * 64 * 256];
    const int tid = threadIdx.x;
    const int n0 = blockIdx.x * 64;
    char* const zh = zz;
    char* const zl = zz + 64 * 256;

    for (int u = tid; u < 64 * 16; u += 384) {
        int e = u >> 4, c16 = u & 15;
        int node = n0 + e;
        unsigned short th[8], tl[8];
        if (c16 < 12 && node < N_NODES) {
            float v[8];
            load8f(in0 + (size_t)node * NF, c16, v);
            if (SMODE == 1) {
                float v1[8];
                load8f(in1 + (size_t)node * NF, c16, v1);
#pragma unroll
                for (int j = 0; j < 8; ++j) v[j] = fast_silu(v[j] + v1[j]);
            }
#pragma unroll
            for (int j = 0; j < 8; ++j) {
                unsigned short hi = f2bf(v[j]);
                th[j] = hi;
                tl[j] = f2bf(v[j] - bf2f(hi));
            }
        } else {
#pragma unroll
            for (int j = 0; j < 8; ++j) { th[j] = 0; tl[j] = 0; }
        }
        int byte = (c16 * 16) ^ ((e & 7) << 4);
        *(uint4*)(zh + e * 256 + byte) = *(uint4*)th;
        *(uint4*)(zl + e * 256 + byte) = *(uint4*)tl;
    }
    __syncthreads();

    const int w = tid >> 6, lane = tid & 63, lr = lane & 15, lg = lane >> 4;
    const int col = w * 16 + lr;
    const float bv = (col < NF) ? b[col] : 0.f;

    f32x4 acc[4];
#pragma unroll
    for (int m = 0; m < 4; ++m) acc[m] = (f32x4){0.f, 0.f, 0.f, 0.f};

#pragma unroll
    for (int ks = 0; ks < 3; ++ks) {
        bf16x8 bh = *(const bf16x8*)(Wh + ((size_t)(ks * 6 + w) * 64 + lane) * 8);
        bf16x8 bl = *(const bf16x8*)(Wl + ((size_t)(ks * 6 + w) * 64 + lane) * 8);
#pragma unroll
        for (int m = 0; m < 4; ++m) {
            int row  = m * 16 + lr;
            int byte = (ks * 64 + lg * 16) ^ ((row & 7) << 4);
            bf16x8 ah = *(const bf16x8*)(zh + row * 256 + byte);
            bf16x8 al = *(const bf16x8*)(zl + row * 256 + byte);
            acc[m] = __builtin_amdgcn_mfma_f32_16x16x32_bf16(ah, bh, acc[m], 0, 0, 0);
            acc[m] = __builtin_amdgcn_mfma_f32_16x16x32_bf16(ah, bl, acc[m], 0, 0, 0);
            acc[m] = __builtin_amdgcn_mfma_f32_16x16x32_bf16(al, bh, acc[m], 0, 0, 0);
        }
    }

    if (POOL) {
        float psum = 0.f;
#pragma unroll
        for (int m = 0; m < 4; ++m)
#pragma unroll
            for (int r = 0; r < 4; ++r) {
                int node = n0 + m * 16 + lg * 4 + r;
                if (node < N_NODES && col < NF)
                    psum += fast_silu(acc[m][r] + bv);
            }
        psum += __shfl_down(psum, 32);
        psum += __shfl_down(psum, 16);
        if (lg == 0 && col < NF) atomicAdd(&outp[col], psum);
    } else {
#pragma unroll
        for (int m = 0; m < 4; ++m)
#pragma unroll
            for (int r = 0; r < 4; ++r) {
                int node = n0 + m * 16 + lg * 4 + r;
                if (node < N_NODES && col < NF)
                    outp[(size_t)node * NF + col] = fast_silu(acc[m][r] + bv);
            }
    }
}

// ---------------- split MLP head ----------------
__global__ __launch_bounds__(128) void mlp_a(const float* __restrict__ pooled,
                                             const float* __restrict__ glob,
                                             const float* __restrict__ W2,
                                             const float* __restrict__ b2,
                                             float* __restrict__ g1)
{
    __shared__ float vin[NF + GF];
    const int t = threadIdx.x;
    for (int i = t; i < NF + GF; i += 128)
        vin[i] = (i < NF) ? pooled[i] * (1.0f / (float)N_NODES) : glob[i - NF];
    __syncthreads();
    const int col = blockIdx.x * 128 + t;
    float a = b2[col];
    for (int k = 0; k < NF + GF; ++k) a = fmaf(vin[k], W2[k * 1024 + col], a);
    g1[col] = fast_silu(a);
}

__global__ __launch_bounds__(128) void mlp_b(const float* __restrict__ g1,
                                             const float* __restrict__ W3,
                                             const float* __restrict__ b3,
                                             float* __restrict__ g2)
{
    __shared__ float vin[1024];
    const int t = threadIdx.x;
    for (int i = t; i < 1024; i += 128) vin[i] = g1[i];
    __syncthreads();
    const int col = blockIdx.x * 128 + t;
    float a = b3[col];
    for (int k = 0; k < 1024; ++k) a = fmaf(vin[k], W3[k * 512 + col], a);
    g2[col] = fast_silu(a);
}

__global__ __launch_bounds__(512) void mlp_c(const float* __restrict__ g2,
    const float* __restrict__ W4, const float* __restrict__ b4,
    const float* __restrict__ W5, const float* __restrict__ b5,
    const float* __restrict__ W6, const float* __restrict__ b6,
    const float* __restrict__ W7, const float* __restrict__ b7,
    float* __restrict__ out)
{
    __shared__ float va[512], vb[256];
    const int t = threadIdx.x;
    va[t] = g2[t];
    __syncthreads();

    if (t < 256) { // fc4: 512 -> 256
        float a = b4[t];
        for (int k = 0; k < 512; ++k) a = fmaf(va[k], W4[k * 256 + t], a);
        vb[t] = fast_silu(a);
    }
    __syncthreads();
    if (t < 128) { // fc5: 256 -> 128
        float a = b5[t];
        for (int k = 0; k < 256; ++k) a = fmaf(vb[k], W5[k * 128 + t], a);
        va[t] = fast_silu(a);
    }
    __syncthreads();
    if (t < 64) { // fc6: 128 -> 64
        float a = b6[t];
        for (int k = 0; k < 128; ++k) a = fmaf(va[k], W6[k * 64 + t], a);
        vb[t] = fast_silu(a);
    }
    __syncthreads();
    if (t < 64) { // fc7: 64 -> 1
        float p = vb[t] * W7[t];
        for (int off = 32; off; off >>= 1) p += __shfl_down(p, off);
        if (t == 0) out[0] = p + b7[0];
    }
}

// ---------------- launch ----------------
extern "C" void kernel_launch(void* const* d_in, const int* in_sizes, int n_in,
                              void* d_out, int out_size, void* d_ws, size_t ws_size,
                              hipStream_t stream)
{
    (void)in_sizes; (void)n_in; (void)out_size;

    const float* x    = (const float*)d_in[0];
    const int*   ei   = (const int*)d_in[1];
    const float* ea   = (const float*)d_in[2];
    const float* glob = (const float*)d_in[3];
    const float* cWf[3] = {(const float*)d_in[5],  (const float*)d_in[9],  (const float*)d_in[13]};
    const float* cbf[3] = {(const float*)d_in[6],  (const float*)d_in[10], (const float*)d_in[14]};
    const float* cWs[3] = {(const float*)d_in[7],  (const float*)d_in[11], (const float*)d_in[15]};
    const float* cbs[3] = {(const float*)d_in[8],  (const float*)d_in[12], (const float*)d_in[16]};
    const float* fc1W = (const float*)d_in[17]; const float* fc1b = (const float*)d_in[18];
    const float* W2 = (const float*)d_in[19];   const float* b2 = (const float*)d_in[20];
    const float* W3 = (const float*)d_in[21];   const float* b3 = (const float*)d_in[22];
    const float* W4 = (const float*)d_in[23];   const float* b4 = (const float*)d_in[24];
    const float* W5 = (const float*)d_in[25];   const float* b5 = (const float*)d_in[26];
    const float* W6 = (const float*)d_in[27];   const float* b6 = (const float*)d_in[28];
    const float* W7 = (const float*)d_in[29];   const float* b7 = (const float*)d_in[30];
    float* out = (float*)d_out;

    const size_t H = (size_t)N_NODES * NF;
    float* h1   = (float*)d_ws;                              // fp32 node state
    float* h2   = h1 + H;
    float* aggA = h2 + H;
    float* aggB = aggA + H;
    float* pooled = aggB + H;                                // 128
    float* g1 = pooled + 128;                                // 1024
    float* g2 = g1 + 1024;                                   // 512
    unsigned short* WcNh = (unsigned short*)(g2 + 512);      // 3*36864 bf16
    unsigned short* WcNl = WcNh + 3 * (size_t)36864;
    unsigned short* WcFh = WcNl + 3 * (size_t)36864;         // 9216 bf16
    unsigned short* WcFl = WcFh + (size_t)WCF_ELEMS;
    _Float16* WcEh = (_Float16*)(WcFl + (size_t)WCF_ELEMS);  // 3*12288 f16
    _Float16* Dh = WcEh + 3 * (size_t)12288;                 // N*96 f16x2
    _Float16* Sh = Dh + (size_t)2 * N_NODES * 96;            // N*96 f16x2
    int* bins   = (int*)(Sh + (size_t)2 * N_NODES * 96);
    int* cursor = bins + N_NODES;
    int* perm   = cursor + N_NODES;
    int* invp   = perm + N_EDGES;
    int* s_src  = invp + N_EDGES;
    int* s_dst  = s_src + N_EDGES;
    _Float16* ebf = (_Float16*)(s_dst + N_EDGES);            // E*48 f16 (slot order)
    const size_t need_full = (size_t)((char*)(ebf + (size_t)N_EDGES * NEP) - (char*)d_ws);
    const bool use_eb = ws_size >= need_full;

    const int nEdgeBlocks = N_EDGES / EBE;                   // 25000
    const int nNodeBlocks = (N_NODES + 63) / 64;             // 782

    // one-time: sort edges by dst (slot-remapped), scatter ea, convert weights
    hipMemsetAsync(bins, 0, N_NODES * sizeof(int), stream);
    hist_kernel<<<(N_EDGES + 255) / 256, 256, 0, stream>>>(ei, bins);
    scan_kernel<<<1, 1024, 0, stream>>>(bins, cursor);
    place_kernel<<<(N_EDGES + 255) / 256, 256, 0, stream>>>(ei, cursor, perm, invp, s_src, s_dst);
    if (use_eb)
        permute_ea16s<<<(int)(((long)N_EDGES * NEP + 255) / 256), 256, 0, stream>>>(ea, invp, ebf);
    convert_all<<<612, 256, 0, stream>>>(cWf[0], cWs[0], cWf[1], cWs[1], cWf[2], cWs[2],
                                         fc1W, WcNh, WcNl, WcEh, WcFh, WcFl);

    // conv layers (fused: silu+residual+stage+agg-zero inside node_mfma_f)
    node_mfma_f<0><<<nNodeBlocks, 384, 0, stream>>>(x, nullptr, nullptr,
        WcNh, WcNl, cbf[0], cbs[0], Dh, Sh, aggA);
    if (use_eb)
        edge_mfma14<true><<<nEdgeBlocks, 384, 0, stream>>>(s_src, s_dst, perm, ea, ebf,
            WcEh, Dh, Sh, aggA, nEdgeBlocks);
    else
        edge_mfma14<false><<<nEdgeBlocks, 384, 0, stream>>>(s_src, s_dst, perm, ea, ebf,
            WcEh, Dh, Sh, aggA, nEdgeBlocks);

    node_mfma_f<1><<<nNodeBlocks, 384, 0, stream>>>(x, aggA, h1,
        WcNh + (size_t)36864, WcNl + (size_t)36864, cbf[1], cbs[1], Dh, Sh, aggB);
    if (use_eb)
        edge_mfma14<true><<<nEdgeBlocks, 384, 0, stream>>>(s_src, s_dst, perm, ea, ebf,
            WcEh + (size_t)12288, Dh, Sh, aggB, nEdgeBlocks);
    else
        edge_mfma14<false><<<nEdgeBlocks, 384, 0, stream>>>(s_src, s_dst, perm, ea, ebf,
            WcEh + (size_t)12288, Dh, Sh, aggB, nEdgeBlocks);

    node_mfma_f<1><<<nNodeBlocks, 384, 0, stream>>>(h1, aggB, h2,
        WcNh + (size_t)2 * 36864, WcNl + (size_t)2 * 36864, cbf[2], cbs[2], Dh, Sh, aggA);
    if (use_eb)
        edge_mfma14<true><<<nEdgeBlocks, 384, 0, stream>>>(s_src, s_dst, perm, ea, ebf,
            WcEh + (size_t)2 * 12288, Dh, Sh, aggA, nEdgeBlocks);
    else
        edge_mfma14<false><<<nEdgeBlocks, 384, 0, stream>>>(s_src, s_dst, perm, ea, ebf,
            WcEh + (size_t)2 * 12288, Dh, Sh, aggA, nEdgeBlocks);

    // fc1 #1: stage silu(h2 + aggA), write fp32 -> aggB
    fc_mfma_f<1, false><<<nNodeBlocks, 384, 0, stream>>>(h2, aggA, WcFh, WcFl, fc1b, aggB);
    // fc1 #2: stage aggB, fused mean-pool into pooled
    hipMemsetAsync(pooled, 0, NF * sizeof(float), stream);
    fc_mfma_f<0, true><<<nNodeBlocks, 384, 0, stream>>>(aggB, nullptr, WcFh, WcFl, fc1b, pooled);

    // MLP head (split)
    mlp_a<<<8, 128, 0, stream>>>(pooled, glob, W2, b2, g1);
    mlp_b<<<4, 128, 0, stream>>>(g1, W3, b3, g2);
    mlp_c<<<1, 512, 0, stream>>>(g2, W4, b4, W5, b5, W6, b6, W7, b7, out);
}

// Round 17
// 899.065 us; speedup vs baseline: 1.5049x; 1.0530x over previous
//
#include <hip/hip_runtime.h>
#include <math.h>

// ---------------- problem constants ----------------
#define N_NODES 50000
#define N_EDGES 800000
#define NF 92           // node features
#define EF 41           // edge features
#define GF 180          // global attr
#define NEP 48          // padded f16 edge_attr row (dst-sorted)
#define EBE 32          // edges per block in edge kernel

#define WCF_ELEMS (3 * 6 * 64 * 8)    // fc1 weights (bf16 hi/lo)

typedef __attribute__((ext_vector_type(8))) short bf16x8;
typedef __attribute__((ext_vector_type(8))) _Float16 f16x8;
typedef __attribute__((ext_vector_type(2))) _Float16 f16x2;
typedef __attribute__((ext_vector_type(4))) float f32x4;

#define L2E 1.44269504f
#define LN2 0.69314718f

__device__ __forceinline__ float fast_sigmoid(float x) {
    return __builtin_amdgcn_rcpf(1.0f + __builtin_amdgcn_exp2f(-x * L2E));
}
__device__ __forceinline__ float fast_softplus(float x) {
    float t = __builtin_amdgcn_exp2f(-fabsf(x) * L2E);
    return fmaxf(x, 0.0f) + __builtin_amdgcn_logf(1.0f + t) * LN2;
}
__device__ __forceinline__ float fast_silu(float x) { return x * fast_sigmoid(x); }

__device__ __forceinline__ unsigned short f2bf(float x) {
    union { float f; unsigned u; } v; v.f = x;
    unsigned r = v.u + 0x7FFF + ((v.u >> 16) & 1);   // RNE
    return (unsigned short)(r >> 16);
}
__device__ __forceinline__ float bf2f(unsigned short h) {
    union { unsigned u; float f; } v; v.u = ((unsigned)h) << 16; return v.f;
}

// bijective XCD-aware block swizzle (m204 variant)
__device__ __forceinline__ int xcd_swz(int bid, int nwg) {
    int q = nwg >> 3, r = nwg & 7;
    int xcd = bid & 7, idx = bid >> 3;
    return (xcd < r ? xcd * (q + 1) : r * (q + 1) + (xcd - r) * q) + idx;
}

// load 8 fp32 from a 92-float row at cols [c16*8, c16*8+8), zero-padded past 91
__device__ __forceinline__ void load8f(const float* __restrict__ rowp, int c16, float v[8]) {
    if (c16 < 11) {
        float4 a = *(const float4*)(rowp + c16 * 8);
        float4 b = *(const float4*)(rowp + c16 * 8 + 4);
        v[0]=a.x; v[1]=a.y; v[2]=a.z; v[3]=a.w; v[4]=b.x; v[5]=b.y; v[6]=b.z; v[7]=b.w;
    } else {
        float4 a = *(const float4*)(rowp + 88);
        v[0]=a.x; v[1]=a.y; v[2]=a.z; v[3]=a.w; v[4]=0.f; v[5]=0.f; v[6]=0.f; v[7]=0.f;
    }
}

// ---------------- sort infra: counting sort of edges by dst ----------------
__global__ __launch_bounds__(256) void hist_kernel(const int* __restrict__ ei,
                                                   int* __restrict__ bins)
{
    int e = blockIdx.x * 256 + threadIdx.x;
    if (e < N_EDGES) atomicAdd(&bins[ei[N_EDGES + e]], 1);
}

__global__ __launch_bounds__(1024) void scan_kernel(const int* __restrict__ bins,
                                                    int* __restrict__ cursor)
{
    __shared__ int tot[1024];
    const int t = threadIdx.x;
    const int C = (N_NODES + 1023) / 1024;
    const int i0 = t * C, i1 = min(i0 + C, N_NODES);
    int s = 0;
    for (int i = i0; i < i1; ++i) s += bins[i];
    tot[t] = s;
    __syncthreads();
    for (int off = 1; off < 1024; off <<= 1) {
        int v = (t >= off) ? tot[t - off] : 0;
        __syncthreads();
        tot[t] += v;
        __syncthreads();
    }
    int run = tot[t] - s;   // exclusive base
    for (int i = i0; i < i1; ++i) { cursor[i] = run; run += bins[i]; }
}

// place with slot remap: sorted position q=(grp*32+off) is stored at slot
// grp*32 + m*16 + lg*4 + r where off = lg*8 + m*4 + r. This makes each
// epilogue lane (lg) own 8 CONSECUTIVE dst-sorted edges -> longer merge runs.
__global__ __launch_bounds__(256) void place_kernel(const int* __restrict__ ei,
                                                    int* __restrict__ cursor,
                                                    int* __restrict__ perm,
                                                    int* __restrict__ invp,
                                                    int* __restrict__ s_src,
                                                    int* __restrict__ s_dst)
{
    int e = blockIdx.x * 256 + threadIdx.x;
    if (e < N_EDGES) {
        int d = ei[N_EDGES + e];
        int pos = atomicAdd(&cursor[d], 1);
        int grp = pos >> 5, off = pos & 31;
        int lg = off >> 3, m = (off >> 2) & 1, r = off & 3;
        int slot = (grp << 5) + m * 16 + lg * 4 + r;
        perm[slot] = e;
        invp[e] = slot;
        s_dst[slot] = d;
        s_src[slot] = ei[e];
    }
}

// ---------------- one-time: scatter ea into slot-ordered f16 rows ----------------
// vectorized: 6 threads per edge, each converts 8 cols and issues one 16B store
__global__ __launch_bounds__(256) void permute_ea16v(const float* __restrict__ ea,
                                                     const int* __restrict__ invp,
                                                     _Float16* __restrict__ ebf)
{
    long i = (long)blockIdx.x * 256 + threadIdx.x;
    if (i >= (long)N_EDGES * 6) return;
    long e = i / 6; int g = (int)(i - e * 6);
    const float* ear = ea + e * EF;
    _Float16 t[8];
#pragma unroll
    for (int j = 0; j < 8; ++j) {
        int cc = g * 8 + j;
        t[j] = (_Float16)((cc < EF) ? ear[cc] : 0.0f);
    }
    *(uint4*)(ebf + (size_t)invp[e] * NEP + g * 8) = *(uint4*)t;
}

// ---------------- merged weight conversion (all layers, node+edge+fc) ----------------
__global__ __launch_bounds__(256) void convert_all(
    const float* __restrict__ Wf0, const float* __restrict__ Ws0,
    const float* __restrict__ Wf1, const float* __restrict__ Ws1,
    const float* __restrict__ Wf2, const float* __restrict__ Ws2,
    const float* __restrict__ fc1W,
    unsigned short* __restrict__ WcNh, unsigned short* __restrict__ WcNl,
    _Float16* __restrict__ WcEh,
    unsigned short* __restrict__ WcFh, unsigned short* __restrict__ WcFl)
{
    const int bid = blockIdx.x;
    if (bid < 432) {
        int l = bid / 144;
        int idx = (bid - l * 144) * 256 + threadIdx.x;
        if (idx >= 36864) return;
        const float* Wf = (l == 0) ? Wf0 : (l == 1) ? Wf1 : Wf2;
        const float* Ws = (l == 0) ? Ws0 : (l == 1) ? Ws1 : Ws2;
        int j    = idx & 7;
        int lane = (idx >> 3) & 63;
        int nt   = (idx >> 9) % 24;
        int ks   = idx / (24 * 512);
        int k = ks * 32 + ((lane >> 4) * 8) + j;
        int n = nt * 16 + (lane & 15);
        int t = n / 96, col = n % 96;
        float val = 0.f;
        if (k < 92 && col < 92) {
            const float* W = (t < 2) ? Wf : Ws;
            int rowoff = (t & 1) ? 92 : 0;
            val = W[(rowoff + k) * NF + col];
        }
        unsigned short hi = f2bf(val);
        size_t o = (size_t)l * 36864 + idx;
        WcNh[o] = hi;
        WcNl[o] = f2bf(val - bf2f(hi));
    } else if (bid < 576) {
        int b2 = bid - 432;
        int l = b2 / 48;
        int idx = (b2 - l * 48) * 256 + threadIdx.x;
        if (idx >= 12288) return;
        const float* Wf = (l == 0) ? Wf0 : (l == 1) ? Wf1 : Wf2;
        const float* Ws = (l == 0) ? Ws0 : (l == 1) ? Ws1 : Ws2;
        int j    = idx & 7;
        int lane = (idx >> 3) & 63;
        int nt   = (idx >> 9) % 12;
        int ks   = idx / (12 * 512);
        int k = ks * 32 + ((lane >> 4) * 8) + j;
        int n = nt * 16 + (lane & 15);
        float val = 0.f;
        if (k < EF) {
            if (n < 92)                  val = Wf[(184 + k) * NF + n];
            else if (n >= 96 && n < 188) val = Ws[(184 + k) * NF + (n - 96)];
        }
        WcEh[(size_t)l * 12288 + idx] = (_Float16)val;
    } else {
        int idx = (bid - 576) * 256 + threadIdx.x;
        if (idx >= WCF_ELEMS) return;
        int j    = idx & 7;
        int lane = (idx >> 3) & 63;
        int nt   = (idx >> 9) % 6;
        int ks   = idx / (6 * 512);
        int k = ks * 32 + ((lane >> 4) * 8) + j;
        int n = nt * 16 + (lane & 15);
        float val = (k < 92 && n < 92) ? fc1W[k * NF + n] : 0.f;
        unsigned short hi = f2bf(val);
        WcFh[idx] = hi;
        WcFl[idx] = f2bf(val - bf2f(hi));
    }
}

// ---------------- fused node GEMM ----------------
// Tables: Dh f16x2 {Pf+bf, Ps+bs}; Sh f16x2 {Qf, Qs}
template <int SMODE>
__global__ __launch_bounds__(384) void node_mfma_f(
    const float* __restrict__ in0, const float* __restrict__ in1,
    float* __restrict__ h_out,
    const unsigned short* __restrict__ Wh, const unsigned short* __restrict__ Wl,
    const float* __restrict__ bf, const float* __restrict__ bs,
    _Float16* __restrict__ Dh, _Float16* __restrict__ Sh,
    float* __restrict__ agg_zero)
{
    __shared__ char zz[2 * 64 * 256];     // hi | lo, 256B rows
    const int tid = threadIdx.x;
    const int n0 = blockIdx.x * 64;
    char* const zh = zz;
    char* const zl = zz + 64 * 256;

    for (int u = tid; u < 64 * 23; u += 384) {
        int e = u / 23, q = u - e * 23;
        int node = n0 + e;
        if (node < N_NODES)
            ((float4*)(agg_zero + (size_t)node * NF))[q] = make_float4(0.f, 0.f, 0.f, 0.f);
    }

    for (int u = tid; u < 64 * 16; u += 384) {
        int e = u >> 4, c16 = u & 15;
        int node = n0 + e;
        unsigned short th[8], tl[8];
        if (c16 < 12 && node < N_NODES) {
            float v[8];
            load8f(in0 + (size_t)node * NF, c16, v);
            if (SMODE == 1) {
                float v1[8];
                load8f(in1 + (size_t)node * NF, c16, v1);
#pragma unroll
                for (int j = 0; j < 8; ++j) v[j] = fast_silu(v[j] + v1[j]);
                float* hr = h_out + (size_t)node * NF;
                if (c16 < 11) {
                    *(float4*)(hr + c16 * 8)     = make_float4(v[0], v[1], v[2], v[3]);
                    *(float4*)(hr + c16 * 8 + 4) = make_float4(v[4], v[5], v[6], v[7]);
                } else {
                    *(float4*)(hr + 88) = make_float4(v[0], v[1], v[2], v[3]);
                }
            }
#pragma unroll
            for (int j = 0; j < 8; ++j) {
                unsigned short hi = f2bf(v[j]);
                th[j] = hi;
                tl[j] = f2bf(v[j] - bf2f(hi));
            }
        } else {
#pragma unroll
            for (int j = 0; j < 8; ++j) { th[j] = 0; tl[j] = 0; }
        }
        int byte = (c16 * 16) ^ ((e & 7) << 4);
        *(uint4*)(zh + e * 256 + byte) = *(uint4*)th;
        *(uint4*)(zl + e * 256 + byte) = *(uint4*)tl;
    }
    __syncthreads();

    const int w = tid >> 6, lane = tid & 63, lr = lane & 15, lg = lane >> 4;
    const int col = w * 16 + lr;
    const float bfv = (col < NF) ? bf[col] : 0.f;
    const float bsv = (col < NF) ? bs[col] : 0.f;

    float keepD[4][4], keepS[4][4];

    for (int ntx = 0; ntx < 4; ++ntx) {
        const int nt = w + 6 * ntx;      // table t == ntx, col fixed
        f32x4 acc[4];
#pragma unroll
        for (int m = 0; m < 4; ++m) acc[m] = (f32x4){0.f, 0.f, 0.f, 0.f};

#pragma unroll
        for (int ks = 0; ks < 3; ++ks) {
            bf16x8 bh = *(const bf16x8*)(Wh + ((size_t)(ks * 24 + nt) * 64 + lane) * 8);
            bf16x8 bl = *(const bf16x8*)(Wl + ((size_t)(ks * 24 + nt) * 64 + lane) * 8);
#pragma unroll
            for (int m = 0; m < 4; ++m) {
                int row  = m * 16 + lr;
                int byte = (ks * 64 + lg * 16) ^ ((row & 7) << 4);
                bf16x8 ah = *(const bf16x8*)(zh + row * 256 + byte);
                bf16x8 al = *(const bf16x8*)(zl + row * 256 + byte);
                acc[m] = __builtin_amdgcn_mfma_f32_16x16x32_bf16(ah, bh, acc[m], 0, 0, 0);
                acc[m] = __builtin_amdgcn_mfma_f32_16x16x32_bf16(ah, bl, acc[m], 0, 0, 0);
                acc[m] = __builtin_amdgcn_mfma_f32_16x16x32_bf16(al, bh, acc[m], 0, 0, 0);
            }
        }

        if (col < NF) {
#pragma unroll
            for (int m = 0; m < 4; ++m) {
#pragma unroll
                for (int r = 0; r < 4; ++r) {
                    int node = n0 + m * 16 + lg * 4 + r;
                    if (ntx == 0) keepD[m][r] = acc[m][r] + bfv;        // Pf+bf
                    else if (ntx == 1) keepS[m][r] = acc[m][r];         // Qf
                    else if (ntx == 2) {                                // Ps+bs -> write Dh
                        if (node < N_NODES) {
                            f16x2 hv;
                            hv[0] = (_Float16)keepD[m][r];
                            hv[1] = (_Float16)(acc[m][r] + bsv);
                            *(f16x2*)(Dh + ((size_t)node * 96 + col) * 2) = hv;
                        }
                    } else {                                            // Qs -> write Sh
                        if (node < N_NODES) {
                            f16x2 hv;
                            hv[0] = (_Float16)keepS[m][r];
                            hv[1] = (_Float16)acc[m][r];
                            *(f16x2*)(Sh + ((size_t)node * 96 + col) * 2) = hv;
                        }
                    }
                }
            }
        }
    }
}

// ---------------- edge kernel: slot-permuted edges, cross-m merged atomics ----------------
template <bool EB>
__global__ __launch_bounds__(384) void edge_mfma14(
    const int* __restrict__ s_src, const int* __restrict__ s_dst,
    const int* __restrict__ perm, const float* __restrict__ ea,
    const _Float16* __restrict__ ebf,
    const _Float16* __restrict__ Wh,
    const _Float16* __restrict__ Dh, const _Float16* __restrict__ Sh,
    float* __restrict__ agg, int nblk)
{
    __shared__ char zb[EBE * 128];    // z: 32 edges x 64 f16 (128B rows), swizzled
    __shared__ int sdst[EBE], ssrc[EBE], sperm[EBE];

    const int tid = threadIdx.x;
    const int bid = xcd_swz(blockIdx.x, nblk);
    const size_t e0 = (size_t)bid * EBE;

    if (tid < EBE) {
        ssrc[tid] = s_src[e0 + tid];
        sdst[tid] = s_dst[e0 + tid];
        if (!EB) sperm[tid] = perm[e0 + tid];
    }
    if (!EB) __syncthreads();

    if (tid < EBE * 8) {
        int e = tid >> 3, c16 = tid & 7;
        uint4 v = make_uint4(0u, 0u, 0u, 0u);
        if (EB) {
            if (c16 < 6) v = *(const uint4*)(ebf + (e0 + e) * NEP + c16 * 8);
        } else {
            if (c16 < 6) {
                const float* ear = ea + (size_t)sperm[e] * EF;
                _Float16 t[8];
#pragma unroll
                for (int jj = 0; jj < 8; ++jj) {
                    int cc = c16 * 8 + jj;
                    t[jj] = (_Float16)((cc < EF) ? ear[cc] : 0.0f);
                }
                v = *(uint4*)t;
            }
        }
        int byte = (c16 * 16) ^ ((e & 7) << 4);
        *(uint4*)(zb + e * 128 + byte) = v;
    }
    __syncthreads();

    const int w = tid >> 6, lane = tid & 63, lr = lane & 15, lg = lane >> 4;
    const int c = w * 16 + lr;

    // prefetch BEFORE MFMA: 8 random S half2 + 1 run-start D half2
    f16x2 sv[2][4];
    f16x2 dv0;
#pragma unroll
    for (int m = 0; m < 2; ++m)
#pragma unroll
        for (int r = 0; r < 4; ++r)
            sv[m][r] = *(const f16x2*)(Sh + ((size_t)ssrc[m * 16 + lg * 4 + r] * 96 + c) * 2);
    dv0 = *(const f16x2*)(Dh + ((size_t)sdst[lg * 4] * 96 + c) * 2);

    f32x4 accF[2], accS[2];
#pragma unroll
    for (int m = 0; m < 2; ++m) {
        accF[m] = (f32x4){0.f, 0.f, 0.f, 0.f};
        accS[m] = (f32x4){0.f, 0.f, 0.f, 0.f};
    }

#pragma unroll
    for (int ks = 0; ks < 2; ++ks) {
        f16x8 bF = *(const f16x8*)(Wh + ((size_t)(ks * 12 + w)     * 64 + lane) * 8);
        f16x8 bS = *(const f16x8*)(Wh + ((size_t)(ks * 12 + w + 6) * 64 + lane) * 8);
#pragma unroll
        for (int m = 0; m < 2; ++m) {
            int row  = m * 16 + lr;
            int byte = (ks * 64 + lg * 16) ^ ((row & 7) << 4);
            f16x8 a = *(const f16x8*)(zb + row * 128 + byte);
            accF[m] = __builtin_amdgcn_mfma_f32_16x16x32_f16(a, bF, accF[m], 0, 0, 0);
            accS[m] = __builtin_amdgcn_mfma_f32_16x16x32_f16(a, bS, accS[m], 0, 0, 0);
        }
    }

    // epilogue: f/s = R + D[dst] + S[src]; merge atomics over the lane's
    // 8 consecutive sorted edges (carry run state across m)
    if (c < NF) {
        int prev = sdst[lg * 4];
        float dvx = (float)dv0[0], dvy = (float)dv0[1];
        float accum = 0.f;
#pragma unroll
        for (int m = 0; m < 2; ++m) {
            const int eb0 = m * 16 + lg * 4;
#pragma unroll
            for (int r = 0; r < 4; ++r) {
                int dst = sdst[eb0 + r];
                if (dst != prev) {
                    atomicAdd(&agg[(size_t)prev * NF + c], accum);
                    accum = 0.f;
                    prev = dst;
                    f16x2 hv = *(const f16x2*)(Dh + ((size_t)dst * 96 + c) * 2);
                    dvx = (float)hv[0]; dvy = (float)hv[1];
                }
                float f = accF[m][r] + dvx + (float)sv[m][r][0];
                float s = accS[m][r] + dvy + (float)sv[m][r][1];
                accum += fast_sigmoid(f) * fast_softplus(s);
            }
        }
        atomicAdd(&agg[(size_t)prev * NF + c], accum);
    }
}

// ---------------- fused fc1 via split-bf16 MFMA ----------------
template <int SMODE, bool POOL>
__global__ __launch_bounds__(384) void fc_mfma_f(
    const float* __restrict__ in0, const float* __restrict__ in1,
    const unsigned short* __restrict__ Wh, const unsigned short* __restrict__ Wl,
    const float* __restrict__ b, float* __restrict__ outp)
{
    __shared__ char zz[2 * 64 * 256];
    const int tid = threadIdx.x;
    const int n0 = blockIdx.x * 64;
    char* const zh = zz;
    char* const zl = zz + 64 * 256;

    for (int u = tid; u < 64 * 16; u += 384) {
        int e = u >> 4, c16 = u & 15;
        int node = n0 + e;
        unsigned short th[8], tl[8];
        if (c16 < 12 && node < N_NODES) {
            float v[8];
            load8f(in0 + (size_t)node * NF, c16, v);
            if (SMODE == 1) {
                float v1[8];
                load8f(in1 + (size_t)node * NF, c16, v1);
#pragma unroll
                for (int j = 0; j < 8; ++j) v[j] = fast_silu(v[j] + v1[j]);
            }
#pragma unroll
            for (int j = 0; j < 8; ++j) {
                unsigned short hi = f2bf(v[j]);
                th[j] = hi;
                tl[j] = f2bf(v[j] - bf2f(hi));
            }
        } else {
#pragma unroll
            for (int j = 0; j < 8; ++j) { th[j] = 0; tl[j] = 0; }
        }
        int byte = (c16 * 16) ^ ((e & 7) << 4);
        *(uint4*)(zh + e * 256 + byte) = *(uint4*)th;
        *(uint4*)(zl + e * 256 + byte) = *(uint4*)tl;
    }
    __syncthreads();

    const int w = tid >> 6, lane = tid & 63, lr = lane & 15, lg = lane >> 4;
    const int col = w * 16 + lr;
    const float bv = (col < NF) ? b[col] : 0.f;

    f32x4 acc[4];
#pragma unroll
    for (int m = 0; m < 4; ++m) acc[m] = (f32x4){0.f, 0.f, 0.f, 0.f};

#pragma unroll
    for (int ks = 0; ks < 3; ++ks) {
        bf16x8 bh = *(const bf16x8*)(Wh + ((size_t)(ks * 6 + w) * 64 + lane) * 8);
        bf16x8 bl = *(const bf16x8*)(Wl + ((size_t)(ks * 6 + w) * 64 + lane) * 8);
#pragma unroll
        for (int m = 0; m < 4; ++m) {
            int row  = m * 16 + lr;
            int byte = (ks * 64 + lg * 16) ^ ((row & 7) << 4);
            bf16x8 ah = *(const bf16x8*)(zh + row * 256 + byte);
            bf16x8 al = *(const bf16x8*)(zl + row * 256 + byte);
            acc[m] = __builtin_amdgcn_mfma_f32_16x16x32_bf16(ah, bh, acc[m], 0, 0, 0);
            acc[m] = __builtin_amdgcn_mfma_f32_16x16x32_bf16(ah, bl, acc[m], 0, 0, 0);
            acc[m] = __builtin_amdgcn_mfma_f32_16x16x32_bf16(al, bh, acc[m], 0, 0, 0);
        }
    }

    if (POOL) {
        float psum = 0.f;
#pragma unroll
        for (int m = 0; m < 4; ++m)
#pragma unroll
            for (int r = 0; r < 4; ++r) {
                int node = n0 + m * 16 + lg * 4 + r;
                if (node < N_NODES && col < NF)
                    psum += fast_silu(acc[m][r] + bv);
            }
        psum += __shfl_down(psum, 32);
        psum += __shfl_down(psum, 16);
        if (lg == 0 && col < NF) atomicAdd(&outp[col], psum);
    } else {
#pragma unroll
        for (int m = 0; m < 4; ++m)
#pragma unroll
            for (int r = 0; r < 4; ++r) {
                int node = n0 + m * 16 + lg * 4 + r;
                if (node < N_NODES && col < NF)
                    outp[(size_t)node * NF + col] = fast_silu(acc[m][r] + bv);
            }
    }
}

// ---------------- split MLP head ----------------
__global__ __launch_bounds__(128) void mlp_a(const float* __restrict__ pooled,
                                             const float* __restrict__ glob,
                                             const float* __restrict__ W2,
                                             const float* __restrict__ b2,
                                             float* __restrict__ g1)
{
    __shared__ float vin[NF + GF];
    const int t = threadIdx.x;
    for (int i = t; i < NF + GF; i += 128)
        vin[i] = (i < NF) ? pooled[i] * (1.0f / (float)N_NODES) : glob[i - NF];
    __syncthreads();
    const int col = blockIdx.x * 128 + t;
    float a = b2[col];
    for (int k = 0; k < NF + GF; ++k) a = fmaf(vin[k], W2[k * 1024 + col], a);
    g1[col] = fast_silu(a);
}

__global__ __launch_bounds__(128) void mlp_b(const float* __restrict__ g1,
                                             const float* __restrict__ W3,
                                             const float* __restrict__ b3,
                                             float* __restrict__ g2)
{
    __shared__ float vin[1024];
    const int t = threadIdx.x;
    for (int i = t; i < 1024; i += 128) vin[i] = g1[i];
    __syncthreads();
    const int col = blockIdx.x * 128 + t;
    float a = b3[col];
    for (int k = 0; k < 1024; ++k) a = fmaf(vin[k], W3[k * 512 + col], a);
    g2[col] = fast_silu(a);
}

__global__ __launch_bounds__(512) void mlp_c(const float* __restrict__ g2,
    const float* __restrict__ W4, const float* __restrict__ b4,
    const float* __restrict__ W5, const float* __restrict__ b5,
    const float* __restrict__ W6, const float* __restrict__ b6,
    const float* __restrict__ W7, const float* __restrict__ b7,
    float* __restrict__ out)
{
    __shared__ float va[512], vb[256];
    const int t = threadIdx.x;
    va[t] = g2[t];
    __syncthreads();

    if (t < 256) { // fc4: 512 -> 256
        float a = b4[t];
        for (int k = 0; k < 512; ++k) a = fmaf(va[k], W4[k * 256 + t], a);
        vb[t] = fast_silu(a);
    }
    __syncthreads();
    if (t < 128) { // fc5: 256 -> 128
        float a = b5[t];
        for (int k = 0; k < 256; ++k) a = fmaf(vb[k], W5[k * 128 + t], a);
        va[t] = fast_silu(a);
    }
    __syncthreads();
    if (t < 64) { // fc6: 128 -> 64
        float a = b6[t];
        for (int k = 0; k < 128; ++k) a = fmaf(va[k], W6[k * 64 + t], a);
        vb[t] = fast_silu(a);
    }
    __syncthreads();
    if (t < 64) { // fc7: 64 -> 1
        float p = vb[t] * W7[t];
        for (int off = 32; off; off >>= 1) p += __shfl_down(p, off);
        if (t == 0) out[0] = p + b7[0];
    }
}

// ---------------- launch ----------------
extern "C" void kernel_launch(void* const* d_in, const int* in_sizes, int n_in,
                              void* d_out, int out_size, void* d_ws, size_t ws_size,
                              hipStream_t stream)
{
    (void)in_sizes; (void)n_in; (void)out_size;

    const float* x    = (const float*)d_in[0];
    const int*   ei   = (const int*)d_in[1];
    const float* ea   = (const float*)d_in[2];
    const float* glob = (const float*)d_in[3];
    const float* cWf[3] = {(const float*)d_in[5],  (const float*)d_in[9],  (const float*)d_in[13]};
    const float* cbf[3] = {(const float*)d_in[6],  (const float*)d_in[10], (const float*)d_in[14]};
    const float* cWs[3] = {(const float*)d_in[7],  (const float*)d_in[11], (const float*)d_in[15]};
    const float* cbs[3] = {(const float*)d_in[8],  (const float*)d_in[12], (const float*)d_in[16]};
    const float* fc1W = (const float*)d_in[17]; const float* fc1b = (const float*)d_in[18];
    const float* W2 = (const float*)d_in[19];   const float* b2 = (const float*)d_in[20];
    const float* W3 = (const float*)d_in[21];   const float* b3 = (const float*)d_in[22];
    const float* W4 = (const float*)d_in[23];   const float* b4 = (const float*)d_in[24];
    const float* W5 = (const float*)d_in[25];   const float* b5 = (const float*)d_in[26];
    const float* W6 = (const float*)d_in[27];   const float* b6 = (const float*)d_in[28];
    const float* W7 = (const float*)d_in[29];   const float* b7 = (const float*)d_in[30];
    float* out = (float*)d_out;

    const size_t H = (size_t)N_NODES * NF;
    float* h1   = (float*)d_ws;                              // fp32 node state
    float* h2   = h1 + H;
    float* aggA = h2 + H;
    float* aggB = aggA + H;
    float* pooled = aggB + H;                                // 128
    float* g1 = pooled + 128;                                // 1024
    float* g2 = g1 + 1024;                                   // 512
    unsigned short* WcNh = (unsigned short*)(g2 + 512);      // 3*36864 bf16
    unsigned short* WcNl = WcNh + 3 * (size_t)36864;
    unsigned short* WcFh = WcNl + 3 * (size_t)36864;         // 9216 bf16
    unsigned short* WcFl = WcFh + (size_t)WCF_ELEMS;
    _Float16* WcEh = (_Float16*)(WcFl + (size_t)WCF_ELEMS);  // 3*12288 f16
    _Float16* Dh = WcEh + 3 * (size_t)12288;                 // N*96 f16x2
    _Float16* Sh = Dh + (size_t)2 * N_NODES * 96;            // N*96 f16x2
    int* bins   = (int*)(Sh + (size_t)2 * N_NODES * 96);
    int* cursor = bins + N_NODES;
    int* perm   = cursor + N_NODES;
    int* invp   = perm + N_EDGES;
    int* s_src  = invp + N_EDGES;
    int* s_dst  = s_src + N_EDGES;
    _Float16* ebf = (_Float16*)(s_dst + N_EDGES);            // E*48 f16 (slot order)
    const size_t need_full = (size_t)((char*)(ebf + (size_t)N_EDGES * NEP) - (char*)d_ws);
    const bool use_eb = ws_size >= need_full;

    const int nEdgeBlocks = N_EDGES / EBE;                   // 25000
    const int nNodeBlocks = (N_NODES + 63) / 64;             // 782

    // one-time: sort edges by dst (slot-remapped), scatter ea, convert weights
    hipMemsetAsync(bins, 0, N_NODES * sizeof(int), stream);
    hist_kernel<<<(N_EDGES + 255) / 256, 256, 0, stream>>>(ei, bins);
    scan_kernel<<<1, 1024, 0, stream>>>(bins, cursor);
    place_kernel<<<(N_EDGES + 255) / 256, 256, 0, stream>>>(ei, cursor, perm, invp, s_src, s_dst);
    if (use_eb)
        permute_ea16v<<<(int)(((long)N_EDGES * 6 + 255) / 256), 256, 0, stream>>>(ea, invp, ebf);
    convert_all<<<612, 256, 0, stream>>>(cWf[0], cWs[0], cWf[1], cWs[1], cWf[2], cWs[2],
                                         fc1W, WcNh, WcNl, WcEh, WcFh, WcFl);

    // conv layers (fused: silu+residual+stage+agg-zero inside node_mfma_f)
    node_mfma_f<0><<<nNodeBlocks, 384, 0, stream>>>(x, nullptr, nullptr,
        WcNh, WcNl, cbf[0], cbs[0], Dh, Sh, aggA);
    if (use_eb)
        edge_mfma14<true><<<nEdgeBlocks, 384, 0, stream>>>(s_src, s_dst, perm, ea, ebf,
            WcEh, Dh, Sh, aggA, nEdgeBlocks);
    else
        edge_mfma14<false><<<nEdgeBlocks, 384, 0, stream>>>(s_src, s_dst, perm, ea, ebf,
            WcEh, Dh, Sh, aggA, nEdgeBlocks);

    node_mfma_f<1><<<nNodeBlocks, 384, 0, stream>>>(x, aggA, h1,
        WcNh + (size_t)36864, WcNl + (size_t)36864, cbf[1], cbs[1], Dh, Sh, aggB);
    if (use_eb)
        edge_mfma14<true><<<nEdgeBlocks, 384, 0, stream>>>(s_src, s_dst, perm, ea, ebf,
            WcEh + (size_t)12288, Dh, Sh, aggB, nEdgeBlocks);
    else
        edge_mfma14<false><<<nEdgeBlocks, 384, 0, stream>>>(s_src, s_dst, perm, ea, ebf,
            WcEh + (size_t)12288, Dh, Sh, aggB, nEdgeBlocks);

    node_mfma_f<1><<<nNodeBlocks, 384, 0, stream>>>(h1, aggB, h2,
        WcNh + (size_t)2 * 36864, WcNl + (size_t)2 * 36864, cbf[2], cbs[2], Dh, Sh, aggA);
    if (use_eb)
        edge_mfma14<true><<<nEdgeBlocks, 384, 0, stream>>>(s_src, s_dst, perm, ea, ebf,
            WcEh + (size_t)2 * 12288, Dh, Sh, aggA, nEdgeBlocks);
    else
        edge_mfma14<false><<<nEdgeBlocks, 384, 0, stream>>>(s_src, s_dst, perm, ea, ebf,
            WcEh + (size_t)2 * 12288, Dh, Sh, aggA, nEdgeBlocks);

    // fc1 #1: stage silu(h2 + aggA), write fp32 -> aggB
    fc_mfma_f<1, false><<<nNodeBlocks, 384, 0, stream>>>(h2, aggA, WcFh, WcFl, fc1b, aggB);
    // fc1 #2: stage aggB, fused mean-pool into pooled
    hipMemsetAsync(pooled, 0, NF * sizeof(float), stream);
    fc_mfma_f<0, true><<<nNodeBlocks, 384, 0, stream>>>(aggB, nullptr, WcFh, WcFl, fc1b, pooled);

    // MLP head (split)
    mlp_a<<<8, 128, 0, stream>>>(pooled, glob, W2, b2, g1);
    mlp_b<<<4, 128, 0, stream>>>(g1, W3, b3, g2);
    mlp_c<<<1, 512, 0, stream>>>(g2, W4, b4, W5, b5, W6, b6, W7, b7, out);
}